// Round 1
// baseline (290.153 us; speedup 1.0000x reference)
//
#include <hip/hip_runtime.h>

#define SEQ 2048
#define NHEADS 16
#define DHEAD 64
#define DMODEL 1024
#define NQKV 3072
#define ATT_SCALE 0.125f

typedef __attribute__((ext_vector_type(8))) short bf16x8;
typedef __attribute__((ext_vector_type(4))) short bf16x4;
typedef __attribute__((ext_vector_type(4))) float f32x4;

__device__ __forceinline__ unsigned short f2bf(float f) {
  union { float f; unsigned u; } v; v.f = f;
  unsigned r = v.u + 0x7FFFu + ((v.u >> 16) & 1u);
  return (unsigned short)(r >> 16);
}

// ---------------- RoPE tables: cost/sint [SEQ][32] fp32 ----------------
__global__ void rope_tables_kernel(float* __restrict__ cost, float* __restrict__ sint) {
  int idx = blockIdx.x * blockDim.x + threadIdx.x;   // SEQ*32 threads
  int t = idx >> 5, j = idx & 31;
  float inv = powf(10000.0f, -(float)(2 * j) / 64.0f);
  float a = (float)t * inv;
  cost[idx] = cosf(a);
  sint[idx] = sinf(a);
}

// ---------------- QKV GEMM: [4096x1024] x [1024x3072], fused RoPE + head split ----
// 128x128 tile, 4 waves (2x2), BK=32, mfma_f32_16x16x32_bf16.
__global__ __launch_bounds__(256) void gemm_qkv_kernel(
    const float* __restrict__ X, const float* __restrict__ W,
    unsigned short* __restrict__ Qb, unsigned short* __restrict__ Kb,
    unsigned short* __restrict__ Vb,
    const float* __restrict__ cost, const float* __restrict__ sint) {
  // pad to 40 elems (80B row stride): 16B-aligned for b128, 2-way banks (free)
  __shared__ unsigned short As[128][40];
  __shared__ unsigned short Bs[128][40];   // stored as [col][k]

  const int tid = threadIdx.x;
  const int lane = tid & 63;
  const int w = tid >> 6;
  const int lam = lane & 15;
  const int g = lane >> 4;
  const int wr = w >> 1, wc = w & 1;
  const int rowBase = blockIdx.x * 128;
  const int colBase = blockIdx.y * 128;

  f32x4 acc[4][4];
#pragma unroll
  for (int m = 0; m < 4; ++m)
#pragma unroll
    for (int n = 0; n < 4; ++n) acc[m][n] = (f32x4){0.f, 0.f, 0.f, 0.f};

  for (int kb = 0; kb < 32; ++kb) {
    const int k0 = kb * 32;
    __syncthreads();
    // stage A (x): 128x32 fp32 -> bf16. 1024 float4 loads / 256 thr = 4 each
#pragma unroll
    for (int p = 0; p < 4; ++p) {
      int id = p * 256 + tid;
      int r = id >> 3, kq = (id & 7) * 4;
      const f32x4 xv = *reinterpret_cast<const f32x4*>(&X[(size_t)(rowBase + r) * DMODEL + k0 + kq]);
      bf16x4 hv;
      hv[0] = (short)f2bf(xv[0]); hv[1] = (short)f2bf(xv[1]);
      hv[2] = (short)f2bf(xv[2]); hv[3] = (short)f2bf(xv[3]);
      *reinterpret_cast<bf16x4*>(&As[r][kq]) = hv;
    }
    // stage B (w_qkv): 32x128, transposed into Bs[col][k]
    {
      int col = tid & 127, half = tid >> 7;
      unsigned short tmp[16];
#pragma unroll
      for (int i = 0; i < 16; ++i)
        tmp[i] = f2bf(W[(size_t)(k0 + half * 16 + i) * NQKV + colBase + col]);
      *reinterpret_cast<bf16x8*>(&Bs[col][half * 16]) = *reinterpret_cast<bf16x8*>(&tmp[0]);
      *reinterpret_cast<bf16x8*>(&Bs[col][half * 16 + 8]) = *reinterpret_cast<bf16x8*>(&tmp[8]);
    }
    __syncthreads();
    bf16x8 a[4], b[4];
#pragma unroll
    for (int m = 0; m < 4; ++m)
      a[m] = *reinterpret_cast<bf16x8*>(&As[wr * 64 + m * 16 + lam][g * 8]);
#pragma unroll
    for (int n = 0; n < 4; ++n)
      b[n] = *reinterpret_cast<bf16x8*>(&Bs[wc * 64 + n * 16 + lam][g * 8]);
#pragma unroll
    for (int m = 0; m < 4; ++m)
#pragma unroll
      for (int n = 0; n < 4; ++n)
        acc[m][n] = __builtin_amdgcn_mfma_f32_16x16x32_bf16(a[m], b[n], acc[m][n], 0, 0, 0);
  }

  // epilogue: split q/k/v, apply RoPE to q,k, store bf16 per-head [bh][t][d]
  const int matcol = colBase + wc * 64;          // multiple of 64
  const int mat = matcol >> 10;                  // 0=q 1=k 2=v
  const int cc = matcol & 1023;
  const int h = cc >> 6;
  unsigned short* dst = (mat == 0) ? Qb : (mat == 1) ? Kb : Vb;
#pragma unroll
  for (int m = 0; m < 4; ++m) {
#pragma unroll
    for (int r = 0; r < 4; ++r) {
      int row = rowBase + wr * 64 + m * 16 + g * 4 + r;   // 0..4095
      int bi = row >> 11, t = row & 2047;
      unsigned short* out = &dst[(size_t)((bi * NHEADS + h) * SEQ + t) * DHEAD];
      if (mat == 2) {
#pragma unroll
        for (int n = 0; n < 4; ++n) out[n * 16 + lam] = f2bf(acc[m][n][r]);
      } else {
#pragma unroll
        for (int n = 0; n < 2; ++n) {
          int j = n * 16 + lam;                   // freq index (= d, d<32)
          float c = cost[t * 32 + j], s = sint[t * 32 + j];
          float x0 = acc[m][n][r], x1 = acc[m][n + 2][r];
          out[j] = f2bf(x0 * c - x1 * s);
          out[j + 32] = f2bf(x1 * c + x0 * s);
        }
      }
    }
  }
}

// ---------------- causal flash attention ----------------
// block = 256 thr (4 waves), one (bh, 64-row q-tile); wave handles 16 q rows.
__global__ __launch_bounds__(256) void attn_kernel(
    const unsigned short* __restrict__ Qb, const unsigned short* __restrict__ Kb,
    const unsigned short* __restrict__ Vb, unsigned short* __restrict__ Ob) {
  // XOR-swizzled (16B-chunk ^ row&7) to keep ds_read_b128 2-way (free)
  __shared__ unsigned short Ks[64][64];
  __shared__ unsigned short Vt[64][64];        // transposed: [d][kv]
  __shared__ unsigned short Ps[4][16][64];     // per-wave P re-layout

  const int tid = threadIdx.x;
  const int lane = tid & 63;
  const int w = tid >> 6;
  const int lam = lane & 15;
  const int g = lane >> 4;
  const int qt = blockIdx.x;
  const int bh = blockIdx.y;
  const int qbase = qt * 64;

  // Q A-frags (row = lam, k = d)
  const unsigned short* qrow = &Qb[(size_t)(bh * SEQ + qbase + w * 16 + lam) * DHEAD];
  bf16x8 qa0 = *reinterpret_cast<const bf16x8*>(&qrow[g * 8]);
  bf16x8 qa1 = *reinterpret_cast<const bf16x8*>(&qrow[g * 8 + 32]);

  f32x4 oacc[4];
#pragma unroll
  for (int f = 0; f < 4; ++f) oacc[f] = (f32x4){0.f, 0.f, 0.f, 0.f};
  float mrow[4] = {-1e30f, -1e30f, -1e30f, -1e30f};
  float lrow[4] = {0.f, 0.f, 0.f, 0.f};

  for (int kt = 0; kt <= qt; ++kt) {
    __syncthreads();
    // stage K (row-major, swizzled) and V transposed
#pragma unroll
    for (int p = 0; p < 2; ++p) {
      int id = p * 256 + tid;
      int r = id >> 3, cq = id & 7;
      const size_t gidx = (size_t)(bh * SEQ + kt * 64 + r) * DHEAD + cq * 8;
      bf16x8 kv = *reinterpret_cast<const bf16x8*>(&Kb[gidx]);
      *reinterpret_cast<bf16x8*>(&Ks[r][(cq ^ (r & 7)) * 8]) = kv;
      bf16x8 vv = *reinterpret_cast<const bf16x8*>(&Vb[gidx]);
#pragma unroll
      for (int i = 0; i < 8; ++i) {
        int d = cq * 8 + i;
        Vt[d][(((r >> 3) ^ (d & 7)) * 8) + (r & 7)] = (unsigned short)vv[i];
      }
    }
    __syncthreads();

    // S = Q K^T  (16 q x 64 kv per wave)
    f32x4 sacc[4];
#pragma unroll
    for (int f = 0; f < 4; ++f) sacc[f] = (f32x4){0.f, 0.f, 0.f, 0.f};
#pragma unroll
    for (int f = 0; f < 4; ++f) {
      int krow = f * 16 + lam;
      bf16x8 b0 = *reinterpret_cast<bf16x8*>(&Ks[krow][(g ^ (krow & 7)) * 8]);
      bf16x8 b1 = *reinterpret_cast<bf16x8*>(&Ks[krow][((g + 4) ^ (krow & 7)) * 8]);
      sacc[f] = __builtin_amdgcn_mfma_f32_16x16x32_bf16(qa0, b0, sacc[f], 0, 0, 0);
      sacc[f] = __builtin_amdgcn_mfma_f32_16x16x32_bf16(qa1, b1, sacc[f], 0, 0, 0);
    }

    const bool diag = (kt == qt);
    float pexp[4][4];
#pragma unroll
    for (int r = 0; r < 4; ++r) {
      int qi = w * 16 + g * 4 + r;   // q row within 64-tile
      float mx = -1e30f;
#pragma unroll
      for (int f = 0; f < 4; ++f) {
        float s = sacc[f][r] * ATT_SCALE;
        if (diag && (f * 16 + lam > qi)) s = -1e30f;
        sacc[f][r] = s;
        mx = fmaxf(mx, s);
      }
      mx = fmaxf(mx, __shfl_xor(mx, 1));
      mx = fmaxf(mx, __shfl_xor(mx, 2));
      mx = fmaxf(mx, __shfl_xor(mx, 4));
      mx = fmaxf(mx, __shfl_xor(mx, 8));
      float mn = fmaxf(mrow[r], mx);
      float alpha = __expf(mrow[r] - mn);
      mrow[r] = mn;
      float sum = 0.f;
#pragma unroll
      for (int f = 0; f < 4; ++f) {
        float p = __expf(sacc[f][r] - mn);
        pexp[f][r] = p;
        sum += p;
      }
      sum += __shfl_xor(sum, 1);
      sum += __shfl_xor(sum, 2);
      sum += __shfl_xor(sum, 4);
      sum += __shfl_xor(sum, 8);
      lrow[r] = lrow[r] * alpha + sum;
#pragma unroll
      for (int f = 0; f < 4; ++f) oacc[f][r] *= alpha;
    }

    // P: D-layout -> A-layout via per-wave LDS (no barrier needed: own region)
#pragma unroll
    for (int r = 0; r < 4; ++r) {
      int i = g * 4 + r;
#pragma unroll
      for (int f = 0; f < 4; ++f) {
        int e = f * 16 + lam;
        Ps[w][i][(((e >> 3) ^ (i & 7)) * 8) + (e & 7)] = f2bf(pexp[f][r]);
      }
    }
    bf16x8 pa0 = *reinterpret_cast<bf16x8*>(&Ps[w][lam][(g ^ (lam & 7)) * 8]);
    bf16x8 pa1 = *reinterpret_cast<bf16x8*>(&Ps[w][lam][((g + 4) ^ (lam & 7)) * 8]);
#pragma unroll
    for (int f = 0; f < 4; ++f) {
      int vrow = f * 16 + lam;
      bf16x8 vb0 = *reinterpret_cast<bf16x8*>(&Vt[vrow][(g ^ (vrow & 7)) * 8]);
      bf16x8 vb1 = *reinterpret_cast<bf16x8*>(&Vt[vrow][((g + 4) ^ (vrow & 7)) * 8]);
      oacc[f] = __builtin_amdgcn_mfma_f32_16x16x32_bf16(pa0, vb0, oacc[f], 0, 0, 0);
      oacc[f] = __builtin_amdgcn_mfma_f32_16x16x32_bf16(pa1, vb1, oacc[f], 0, 0, 0);
    }
  }

  // epilogue: normalize, store bf16 to Ob[b*SEQ+n][h*64+d]
  const int b = bh >> 4, h = bh & 15;
#pragma unroll
  for (int r = 0; r < 4; ++r) {
    int n = qbase + w * 16 + g * 4 + r;
    float inv = 1.0f / lrow[r];
    unsigned short* orow = &Ob[(size_t)(b * SEQ + n) * DMODEL + h * DHEAD];
#pragma unroll
    for (int f = 0; f < 4; ++f) orow[f * 16 + lam] = f2bf(oacc[f][r] * inv);
  }
}

// ---------------- output GEMM: [4096x1024 bf16] x [1024x1024] -> fp32 ----------------
__global__ __launch_bounds__(256) void gemm_out_kernel(
    const unsigned short* __restrict__ A, const float* __restrict__ W,
    float* __restrict__ C) {
  __shared__ unsigned short As[128][40];
  __shared__ unsigned short Bs[128][40];

  const int tid = threadIdx.x;
  const int lane = tid & 63;
  const int w = tid >> 6;
  const int lam = lane & 15;
  const int g = lane >> 4;
  const int wr = w >> 1, wc = w & 1;
  const int rowBase = blockIdx.x * 128;
  const int colBase = blockIdx.y * 128;

  f32x4 acc[4][4];
#pragma unroll
  for (int m = 0; m < 4; ++m)
#pragma unroll
    for (int n = 0; n < 4; ++n) acc[m][n] = (f32x4){0.f, 0.f, 0.f, 0.f};

  for (int kb = 0; kb < 32; ++kb) {
    const int k0 = kb * 32;
    __syncthreads();
#pragma unroll
    for (int p = 0; p < 2; ++p) {
      int id = p * 256 + tid;
      int r = id >> 2, cq = (id & 3) * 8;
      *reinterpret_cast<bf16x8*>(&As[r][cq]) =
          *reinterpret_cast<const bf16x8*>(&A[(size_t)(rowBase + r) * DMODEL + k0 + cq]);
    }
    {
      int col = tid & 127, half = tid >> 7;
      unsigned short tmp[16];
#pragma unroll
      for (int i = 0; i < 16; ++i)
        tmp[i] = f2bf(W[(size_t)(k0 + half * 16 + i) * DMODEL + colBase + col]);
      *reinterpret_cast<bf16x8*>(&Bs[col][half * 16]) = *reinterpret_cast<bf16x8*>(&tmp[0]);
      *reinterpret_cast<bf16x8*>(&Bs[col][half * 16 + 8]) = *reinterpret_cast<bf16x8*>(&tmp[8]);
    }
    __syncthreads();
    bf16x8 a[4], b[4];
#pragma unroll
    for (int m = 0; m < 4; ++m)
      a[m] = *reinterpret_cast<bf16x8*>(&As[wr * 64 + m * 16 + lam][g * 8]);
#pragma unroll
    for (int n = 0; n < 4; ++n)
      b[n] = *reinterpret_cast<bf16x8*>(&Bs[wc * 64 + n * 16 + lam][g * 8]);
#pragma unroll
    for (int m = 0; m < 4; ++m)
#pragma unroll
      for (int n = 0; n < 4; ++n)
        acc[m][n] = __builtin_amdgcn_mfma_f32_16x16x32_bf16(a[m], b[n], acc[m][n], 0, 0, 0);
  }

#pragma unroll
  for (int m = 0; m < 4; ++m)
#pragma unroll
    for (int r = 0; r < 4; ++r) {
      int row = rowBase + wr * 64 + m * 16 + g * 4 + r;
#pragma unroll
      for (int n = 0; n < 4; ++n)
        C[(size_t)row * DMODEL + colBase + wc * 64 + n * 16 + lam] = acc[m][n][r];
    }
}

extern "C" void kernel_launch(void* const* d_in, const int* in_sizes, int n_in,
                              void* d_out, int out_size, void* d_ws, size_t ws_size,
                              hipStream_t stream) {
  const float* x = (const float*)d_in[0];       // [2][2048][1024]
  const float* w_qkv = (const float*)d_in[1];   // [1024][3072]
  const float* w_out = (const float*)d_in[2];   // [1024][1024]
  float* out = (float*)d_out;                   // [2][2048][1024] fp32

  const size_t HBUF = (size_t)2 * NHEADS * SEQ * DHEAD;   // 4M elems
  unsigned short* Qb = (unsigned short*)d_ws;
  unsigned short* Kb = Qb + HBUF;
  unsigned short* Vb = Kb + HBUF;
  unsigned short* Ob = Vb + HBUF;
  float* cost = (float*)(Ob + (size_t)2 * SEQ * DMODEL);
  float* sint = cost + SEQ * 32;

  rope_tables_kernel<<<SEQ * 32 / 256, 256, 0, stream>>>(cost, sint);
  gemm_qkv_kernel<<<dim3(32, 24), 256, 0, stream>>>(x, w_qkv, Qb, Kb, Vb, cost, sint);
  attn_kernel<<<dim3(32, 32), 256, 0, stream>>>(Qb, Kb, Vb, Ob);
  gemm_out_kernel<<<dim3(32, 8), 256, 0, stream>>>(Ob, w_out, out);
}

// Round 2
// 216.342 us; speedup vs baseline: 1.3412x; 1.3412x over previous
//
#include <hip/hip_runtime.h>

#define SEQ 2048
#define NH 16
#define DH 64
#define DMODEL 1024
#define NQKV 3072
#define ATT_SCALE 0.125f

typedef __attribute__((ext_vector_type(8))) short bf16x8;
typedef __attribute__((ext_vector_type(4))) short bf16x4;
typedef __attribute__((ext_vector_type(4))) float f32x4;

#define GLOAD16(src, dst)                                                              \
  __builtin_amdgcn_global_load_lds((const __attribute__((address_space(1))) void*)(src), \
                                   (__attribute__((address_space(3))) void*)(dst), 16, 0, 0)

__device__ __forceinline__ unsigned short f2bf(float f) {
  union { float f; unsigned u; } v; v.f = f;
  unsigned r = v.u + 0x7FFFu + ((v.u >> 16) & 1u);
  return (unsigned short)(r >> 16);
}

// ---------------- RoPE tables: cost/sint [SEQ][32] fp32 ----------------
__global__ void rope_tables_kernel(float* __restrict__ cost, float* __restrict__ sint) {
  int idx = blockIdx.x * blockDim.x + threadIdx.x;
  int t = idx >> 5, j = idx & 31;
  float inv = powf(10000.0f, -(float)(2 * j) / 64.0f);
  float a = (float)t * inv;
  cost[idx] = cosf(a);
  sint[idx] = sinf(a);
}

// ------------- transpose+convert: in f32 [K][N] -> out bf16 [N][K] (32x32 tiles) ----
__global__ __launch_bounds__(256) void transw_kernel(const float* __restrict__ in,
                                                     unsigned short* __restrict__ out,
                                                     int K, int N) {
  __shared__ float Ts[32][33];
  const int tid = threadIdx.x;
  const int k0 = blockIdx.x * 32, n0 = blockIdx.y * 32;
  const int r = tid >> 5, c = tid & 31;
#pragma unroll
  for (int i = 0; i < 4; ++i)
    Ts[8 * i + r][c] = in[(size_t)(k0 + 8 * i + r) * N + n0 + c];
  __syncthreads();
#pragma unroll
  for (int i = 0; i < 4; ++i)
    out[(size_t)(n0 + 8 * i + r) * K + k0 + c] = f2bf(Ts[c][8 * i + r]);
}

// ---------------- QKV GEMM: X[4096x1024]f32 x WqkvT[3072x1024]bf16 ----------------
// 128x128 tile, 4 waves, BK=32. RoPE epilogue for Q/K; LDS-transpose epilogue for V.
__global__ __launch_bounds__(256) void gemm_qkv_kernel(
    const float* __restrict__ X, const unsigned short* __restrict__ BT,
    unsigned short* __restrict__ Qb, unsigned short* __restrict__ Kb,
    unsigned short* __restrict__ Vtg,
    const float* __restrict__ cost, const float* __restrict__ sint) {
  __shared__ unsigned short As[128][32];
  __shared__ unsigned short Bs[128][32];
  __shared__ unsigned short Vbuf[128][40];

  const int tid = threadIdx.x;
  const int lane = tid & 63;
  const int w = tid >> 6;
  const int lam = lane & 15;
  const int g = lane >> 4;
  const int wr = w >> 1, wc = w & 1;
  const int rowBase = blockIdx.x * 128;
  const int colBase = blockIdx.y * 128;

  f32x4 acc[4][4];
#pragma unroll
  for (int m = 0; m < 4; ++m)
#pragma unroll
    for (int n = 0; n < 4; ++n) acc[m][n] = (f32x4){0.f, 0.f, 0.f, 0.f};

  for (int kb = 0; kb < 32; ++kb) {
    const int k0 = kb * 32;
    __syncthreads();
    // stage A: fp32 -> bf16 conversion staging
#pragma unroll
    for (int p = 0; p < 4; ++p) {
      int id = p * 256 + tid;
      int r = id >> 3, kq = (id & 7) * 4;
      const f32x4 xv = *reinterpret_cast<const f32x4*>(&X[(size_t)(rowBase + r) * DMODEL + k0 + kq]);
      bf16x4 hv;
      hv[0] = (short)f2bf(xv[0]); hv[1] = (short)f2bf(xv[1]);
      hv[2] = (short)f2bf(xv[2]); hv[3] = (short)f2bf(xv[3]);
      *reinterpret_cast<bf16x4*>(&As[r][kq]) = hv;
    }
    // stage B via global_load_lds (BT row-major along k; linear LDS)
#pragma unroll
    for (int c = 0; c < 2; ++c) {
      int ch = c * 256 + w * 64 + lane;
      int row = ch >> 2, q = ch & 3;
      GLOAD16(BT + (size_t)(colBase + row) * DMODEL + k0 + q * 8,
              &Bs[0][0] + (c * 256 + w * 64) * 8);
    }
    asm volatile("s_waitcnt vmcnt(0)" ::: "memory");
    __syncthreads();
    bf16x8 a[4], b[4];
#pragma unroll
    for (int m = 0; m < 4; ++m)
      a[m] = *reinterpret_cast<bf16x8*>(&As[wr * 64 + m * 16 + lam][g * 8]);
#pragma unroll
    for (int n = 0; n < 4; ++n)
      b[n] = *reinterpret_cast<bf16x8*>(&Bs[wc * 64 + n * 16 + lam][g * 8]);
#pragma unroll
    for (int m = 0; m < 4; ++m)
#pragma unroll
      for (int n = 0; n < 4; ++n)
        acc[m][n] = __builtin_amdgcn_mfma_f32_16x16x32_bf16(a[m], b[n], acc[m][n], 0, 0, 0);
  }

  const int mat = blockIdx.y >> 3;   // 0=Q 1=K 2=V (block-uniform)
  if (mat < 2) {
    unsigned short* dst = mat ? Kb : Qb;
    const int h = ((colBase & 1023) + wc * 64) >> 6;
#pragma unroll
    for (int m = 0; m < 4; ++m) {
#pragma unroll
      for (int r = 0; r < 4; ++r) {
        int row = rowBase + wr * 64 + m * 16 + g * 4 + r;
        int bi = row >> 11, t = row & 2047;
        unsigned short* out = &dst[(size_t)((bi * NH + h) * SEQ + t) * DH];
#pragma unroll
        for (int n = 0; n < 2; ++n) {
          int j = n * 16 + lam;
          float c = cost[t * 32 + j], s = sint[t * 32 + j];
          float x0 = acc[m][n][r], x1 = acc[m][n + 2][r];
          out[j] = f2bf(x0 * c - x1 * s);
          out[j + 32] = f2bf(x1 * c + x0 * s);
        }
      }
    }
  } else {
    // V: transpose 128x128 via LDS in 4 chunks of 32 cols -> Vtg[bh][d][t]
    const int b = rowBase >> 11, t0 = rowBase & 2047;
#pragma unroll
    for (int cc = 0; cc < 4; ++cc) {
      __syncthreads();
      if (wc == (cc >> 1)) {
        const int n0 = (cc & 1) * 2;
#pragma unroll
        for (int m = 0; m < 4; ++m)
#pragma unroll
          for (int r = 0; r < 4; ++r)
#pragma unroll
            for (int n2 = 0; n2 < 2; ++n2)
              Vbuf[wr * 64 + m * 16 + g * 4 + r][n2 * 16 + lam] = f2bf(acc[m][n0 + n2][r]);
      }
      __syncthreads();
      const int colq0 = colBase - 2048 + cc * 32;
#pragma unroll
      for (int p2 = 0; p2 < 2; ++p2) {
        int ch = p2 * 256 + tid;
        int d = ch & 31, tq = (ch >> 5) * 8;
        unsigned short tmp[8];
#pragma unroll
        for (int i = 0; i < 8; ++i) tmp[i] = Vbuf[tq + i][d];
        int col = colq0 + d;
        int h = col >> 6, dd = col & 63;
        *reinterpret_cast<bf16x8*>(&Vtg[((size_t)(b * NH + h) * DH + dd) * SEQ + t0 + tq]) =
            *reinterpret_cast<bf16x8*>(tmp);
      }
    }
  }
}

// ---------------- causal flash attention (balanced pairs + KV dbuf) ----------------
// block = 256 thr (4 waves); blockIdx.x = pair p in 0..15; processes q-tiles p and 31-p
// sequentially => exactly 33 kv-iterations per block. KV double-buffered in LDS via
// global_load_lds with pre-swizzled source.
__global__ __launch_bounds__(256) void attn_kernel(
    const unsigned short* __restrict__ Qb, const unsigned short* __restrict__ Kb,
    const unsigned short* __restrict__ Vtg, unsigned short* __restrict__ Ob) {
  __shared__ unsigned short Ks[2][4096];   // [buf][64 kv rows][64 d], 16B-chunk XOR swizzle
  __shared__ unsigned short Vs[2][4096];   // [buf][64 d rows][64 kv], same swizzle
  __shared__ unsigned short Ps[4][16][72]; // per-wave P relayout, +8 pad

  const int tid = threadIdx.x;
  const int lane = tid & 63;
  const int w = tid >> 6;
  const int lam = lane & 15;
  const int g = lane >> 4;
  const int p = blockIdx.x;       // 0..15
  const int bh = blockIdx.y;      // 0..31
  const int qtA = p, qtB = 31 - p;

  const unsigned short* kallbase = Kb + (size_t)bh * SEQ * DH;
  const unsigned short* vallbase = Vtg + (size_t)bh * DH * SEQ;

  bf16x8 qa0, qa1;
  f32x4 oacc[4];
  float mrow[4], lrow[4];

  // ---- helpers as macros (block-uniform control flow) ----
#define LOADQ(qt)                                                                     \
  {                                                                                   \
    const unsigned short* qrow = Qb + ((size_t)bh * SEQ + (qt) * 64 + w * 16 + lam) * DH; \
    qa0 = *reinterpret_cast<const bf16x8*>(&qrow[g * 8]);                             \
    qa1 = *reinterpret_cast<const bf16x8*>(&qrow[g * 8 + 32]);                        \
  }
#define RESET_STATE()                                                                 \
  {                                                                                   \
    _Pragma("unroll") for (int f = 0; f < 4; ++f) oacc[f] = (f32x4){0.f, 0.f, 0.f, 0.f}; \
    _Pragma("unroll") for (int r = 0; r < 4; ++r) { mrow[r] = -1e30f; lrow[r] = 0.f; } \
  }
#define STAGE(buf, kt)                                                                \
  {                                                                                   \
    const unsigned short* kb2 = kallbase + (size_t)(kt) * 64 * DH;                    \
    const unsigned short* vb2 = vallbase + (size_t)(kt) * 64;                         \
    _Pragma("unroll") for (int c = 0; c < 2; ++c) {                                   \
      int ch = c * 256 + w * 64 + lane;                                               \
      int row = ch >> 3, q = ch & 7;                                                  \
      GLOAD16(kb2 + row * DH + ((q ^ (row & 7)) * 8),                                 \
              &Ks[buf][0] + (c * 256 + w * 64) * 8);                                  \
      GLOAD16(vb2 + (size_t)row * SEQ + ((q ^ (row & 7)) * 8),                        \
              &Vs[buf][0] + (c * 256 + w * 64) * 8);                                  \
    }                                                                                 \
  }
#define FLUSHO(qt)                                                                    \
  {                                                                                   \
    const int b = bh >> 4, h = bh & 15;                                               \
    _Pragma("unroll") for (int r = 0; r < 4; ++r) {                                   \
      int n = (qt) * 64 + w * 16 + g * 4 + r;                                         \
      float inv = 1.0f / lrow[r];                                                     \
      unsigned short* orow = &Ob[(size_t)(b * SEQ + n) * DMODEL + h * DH];            \
      _Pragma("unroll") for (int f = 0; f < 4; ++f) orow[f * 16 + lam] = f2bf(oacc[f][r] * inv); \
    }                                                                                 \
  }

  RESET_STATE();
  LOADQ(qtA);
  STAGE(0, 0);
  asm volatile("s_waitcnt vmcnt(0)" ::: "memory");
  __syncthreads();

  int cur = 0;
  for (int i = 0; i <= 32; ++i) {
    const int tileB = (i > p);
    const int kt = tileB ? (i - p - 1) : i;
    const int qt = tileB ? qtB : qtA;

    if (i < 32) {
      const int tB2 = (i + 1 > p);
      const int kt2 = tB2 ? (i - p) : (i + 1);
      STAGE(cur ^ 1, kt2);
    }

    // ---- S = Q K^T ----
    f32x4 sacc[4];
#pragma unroll
    for (int f = 0; f < 4; ++f) sacc[f] = (f32x4){0.f, 0.f, 0.f, 0.f};
#pragma unroll
    for (int f = 0; f < 4; ++f) {
      int krow = f * 16 + lam;
      bf16x8 b0 = *reinterpret_cast<bf16x8*>(&Ks[cur][krow * 64 + ((g ^ (krow & 7)) * 8)]);
      bf16x8 b1 = *reinterpret_cast<bf16x8*>(&Ks[cur][krow * 64 + (((g + 4) ^ (krow & 7)) * 8)]);
      sacc[f] = __builtin_amdgcn_mfma_f32_16x16x32_bf16(qa0, b0, sacc[f], 0, 0, 0);
      sacc[f] = __builtin_amdgcn_mfma_f32_16x16x32_bf16(qa1, b1, sacc[f], 0, 0, 0);
    }

    const bool diag = (kt == qt);
    float pexp[4][4];
#pragma unroll
    for (int r = 0; r < 4; ++r) {
      int qi = w * 16 + g * 4 + r;
      float mx = -1e30f;
#pragma unroll
      for (int f = 0; f < 4; ++f) {
        float s = sacc[f][r] * ATT_SCALE;
        if (diag && (f * 16 + lam > qi)) s = -1e30f;
        sacc[f][r] = s;
        mx = fmaxf(mx, s);
      }
      mx = fmaxf(mx, __shfl_xor(mx, 1));
      mx = fmaxf(mx, __shfl_xor(mx, 2));
      mx = fmaxf(mx, __shfl_xor(mx, 4));
      mx = fmaxf(mx, __shfl_xor(mx, 8));
      float mn = fmaxf(mrow[r], mx);
      float alpha = __expf(mrow[r] - mn);
      mrow[r] = mn;
      float sum = 0.f;
#pragma unroll
      for (int f = 0; f < 4; ++f) {
        float pe = __expf(sacc[f][r] - mn);
        pexp[f][r] = pe;
        sum += pe;
      }
      sum += __shfl_xor(sum, 1);
      sum += __shfl_xor(sum, 2);
      sum += __shfl_xor(sum, 4);
      sum += __shfl_xor(sum, 8);
      lrow[r] = lrow[r] * alpha + sum;
#pragma unroll
      for (int f = 0; f < 4; ++f) oacc[f][r] *= alpha;
    }

    // P relayout through padded per-wave LDS
#pragma unroll
    for (int r = 0; r < 4; ++r) {
      int ii = g * 4 + r;
#pragma unroll
      for (int f = 0; f < 4; ++f) Ps[w][ii][f * 16 + lam] = f2bf(pexp[f][r]);
    }
    bf16x8 pa0 = *reinterpret_cast<bf16x8*>(&Ps[w][lam][g * 8]);
    bf16x8 pa1 = *reinterpret_cast<bf16x8*>(&Ps[w][lam][32 + g * 8]);
#pragma unroll
    for (int f = 0; f < 4; ++f) {
      int vrow = f * 16 + lam;
      bf16x8 vb0 = *reinterpret_cast<bf16x8*>(&Vs[cur][vrow * 64 + ((g ^ (vrow & 7)) * 8)]);
      bf16x8 vb1 = *reinterpret_cast<bf16x8*>(&Vs[cur][vrow * 64 + (((g + 4) ^ (vrow & 7)) * 8)]);
      oacc[f] = __builtin_amdgcn_mfma_f32_16x16x32_bf16(pa0, vb0, oacc[f], 0, 0, 0);
      oacc[f] = __builtin_amdgcn_mfma_f32_16x16x32_bf16(pa1, vb1, oacc[f], 0, 0, 0);
    }

    if (i == p) {  // finished q-tile A: flush, reset, switch to B
      FLUSHO(qtA);
      RESET_STATE();
      LOADQ(qtB);
    }

    asm volatile("s_waitcnt vmcnt(0)" ::: "memory");
    __syncthreads();
    cur ^= 1;
  }
  FLUSHO(qtB);
#undef LOADQ
#undef RESET_STATE
#undef STAGE
#undef FLUSHO
}

// ---------------- output GEMM: Ob[4096x1024]bf16 x WoutT[1024x1024]bf16 -> f32 ----
__global__ __launch_bounds__(256) void gemm_out_kernel(
    const unsigned short* __restrict__ A, const unsigned short* __restrict__ BT,
    float* __restrict__ C) {
  __shared__ unsigned short As[128][32];
  __shared__ unsigned short Bs[128][32];

  const int tid = threadIdx.x;
  const int lane = tid & 63;
  const int w = tid >> 6;
  const int lam = lane & 15;
  const int g = lane >> 4;
  const int wr = w >> 1, wc = w & 1;
  const int rowBase = blockIdx.x * 128;
  const int colBase = blockIdx.y * 128;

  f32x4 acc[4][4];
#pragma unroll
  for (int m = 0; m < 4; ++m)
#pragma unroll
    for (int n = 0; n < 4; ++n) acc[m][n] = (f32x4){0.f, 0.f, 0.f, 0.f};

  for (int kb = 0; kb < 32; ++kb) {
    const int k0 = kb * 32;
    __syncthreads();
#pragma unroll
    for (int c = 0; c < 2; ++c) {
      int ch = c * 256 + w * 64 + lane;
      int row = ch >> 2, q = ch & 3;
      GLOAD16(A + (size_t)(rowBase + row) * DMODEL + k0 + q * 8,
              &As[0][0] + (c * 256 + w * 64) * 8);
      GLOAD16(BT + (size_t)(colBase + row) * DMODEL + k0 + q * 8,
              &Bs[0][0] + (c * 256 + w * 64) * 8);
    }
    asm volatile("s_waitcnt vmcnt(0)" ::: "memory");
    __syncthreads();
    bf16x8 a[4], b[4];
#pragma unroll
    for (int m = 0; m < 4; ++m)
      a[m] = *reinterpret_cast<bf16x8*>(&As[wr * 64 + m * 16 + lam][g * 8]);
#pragma unroll
    for (int n = 0; n < 4; ++n)
      b[n] = *reinterpret_cast<bf16x8*>(&Bs[wc * 64 + n * 16 + lam][g * 8]);
#pragma unroll
    for (int m = 0; m < 4; ++m)
#pragma unroll
      for (int n = 0; n < 4; ++n)
        acc[m][n] = __builtin_amdgcn_mfma_f32_16x16x32_bf16(a[m], b[n], acc[m][n], 0, 0, 0);
  }

#pragma unroll
  for (int m = 0; m < 4; ++m)
#pragma unroll
    for (int r = 0; r < 4; ++r) {
      int row = rowBase + wr * 64 + m * 16 + g * 4 + r;
#pragma unroll
      for (int n = 0; n < 4; ++n)
        C[(size_t)row * DMODEL + colBase + wc * 64 + n * 16 + lam] = acc[m][n][r];
    }
}

extern "C" void kernel_launch(void* const* d_in, const int* in_sizes, int n_in,
                              void* d_out, int out_size, void* d_ws, size_t ws_size,
                              hipStream_t stream) {
  const float* x = (const float*)d_in[0];       // [2][2048][1024]
  const float* w_qkv = (const float*)d_in[1];   // [1024][3072]
  const float* w_out = (const float*)d_in[2];   // [1024][1024]
  float* out = (float*)d_out;

  char* ws = (char*)d_ws;
  const size_t MB = 1024 * 1024;
  // region [0,8MB): WqkvT (6MB) + rope tables (0.5MB) during phase 1; Ob (8MB) afterwards
  unsigned short* WqkvT = (unsigned short*)(ws);
  float* cost = (float*)(ws + 6 * MB);
  float* sint = cost + SEQ * 32;
  unsigned short* Ob = (unsigned short*)(ws);
  unsigned short* WoutT = (unsigned short*)(ws + 8 * MB);    // 2MB
  unsigned short* Qb = (unsigned short*)(ws + 10 * MB);      // 8MB
  unsigned short* Kb = (unsigned short*)(ws + 18 * MB);      // 8MB
  unsigned short* Vtg = (unsigned short*)(ws + 26 * MB);     // 8MB   [bh][d][t]

  rope_tables_kernel<<<SEQ * 32 / 256, 256, 0, stream>>>(cost, sint);
  transw_kernel<<<dim3(32, 96), 256, 0, stream>>>(w_qkv, WqkvT, DMODEL, NQKV);
  transw_kernel<<<dim3(32, 32), 256, 0, stream>>>(w_out, WoutT, DMODEL, DMODEL);
  gemm_qkv_kernel<<<dim3(32, 24), 256, 0, stream>>>(x, WqkvT, Qb, Kb, Vtg, cost, sint);
  attn_kernel<<<dim3(16, 32), 256, 0, stream>>>(Qb, Kb, Vtg, Ob);
  gemm_out_kernel<<<dim3(32, 8), 256, 0, stream>>>(Ob, WoutT, out);
}

// Round 3
// 168.831 us; speedup vs baseline: 1.7186x; 1.2814x over previous
//
#include <hip/hip_runtime.h>

#define SEQ 2048
#define NH 16
#define DH 64
#define DMODEL 1024
#define NQKV 3072
#define ATT_SCALE 0.125f

typedef __attribute__((ext_vector_type(8))) short bf16x8;
typedef __attribute__((ext_vector_type(4))) short bf16x4;
typedef __attribute__((ext_vector_type(4))) float f32x4;

#define GLOAD16(src, dst)                                                              \
  __builtin_amdgcn_global_load_lds((const __attribute__((address_space(1))) void*)(src), \
                                   (__attribute__((address_space(3))) void*)(dst), 16, 0, 0)

__device__ __forceinline__ unsigned short f2bf(float f) {
  union { float f; unsigned u; } v; v.f = f;
  unsigned r = v.u + 0x7FFFu + ((v.u >> 16) & 1u);
  return (unsigned short)(r >> 16);
}

// ---------------- RoPE tables: cost/sint [SEQ][32] fp32 ----------------
__global__ void rope_tables_kernel(float* __restrict__ cost, float* __restrict__ sint) {
  int idx = blockIdx.x * blockDim.x + threadIdx.x;
  int t = idx >> 5, j = idx & 31;
  float inv = powf(10000.0f, -(float)(2 * j) / 64.0f);
  float a = (float)t * inv;
  cost[idx] = cosf(a);
  sint[idx] = sinf(a);
}

// ---------------- X fp32 -> bf16 (into d_out scratch) ----------------
__global__ __launch_bounds__(256) void x2bf_kernel(const float* __restrict__ in,
                                                   unsigned short* __restrict__ out) {
  int idx = blockIdx.x * 256 + threadIdx.x;   // 2048 blocks, 8 elems/thread
  const f32x4 v0 = *reinterpret_cast<const f32x4*>(&in[(size_t)idx * 8]);
  const f32x4 v1 = *reinterpret_cast<const f32x4*>(&in[(size_t)idx * 8 + 4]);
  bf16x8 o;
  o[0] = (short)f2bf(v0[0]); o[1] = (short)f2bf(v0[1]);
  o[2] = (short)f2bf(v0[2]); o[3] = (short)f2bf(v0[3]);
  o[4] = (short)f2bf(v1[0]); o[5] = (short)f2bf(v1[1]);
  o[6] = (short)f2bf(v1[2]); o[7] = (short)f2bf(v1[3]);
  *reinterpret_cast<bf16x8*>(&out[(size_t)idx * 8]) = o;
}

// ------- transpose+convert: in f32 [K][N] -> out bf16 [N][K], 64x64 tiles -------
__global__ __launch_bounds__(256) void transw_kernel(const float* __restrict__ in,
                                                     unsigned short* __restrict__ out,
                                                     int K, int N) {
  __shared__ float Ts[64][65];
  const int tid = threadIdx.x;
  const int k0 = blockIdx.x * 64, n0 = blockIdx.y * 64;
#pragma unroll
  for (int p = 0; p < 4; ++p) {
    int id = p * 256 + tid;
    int r = id >> 4, c4 = (id & 15) * 4;
    const f32x4 v = *reinterpret_cast<const f32x4*>(&in[(size_t)(k0 + r) * N + n0 + c4]);
    Ts[r][c4] = v[0]; Ts[r][c4 + 1] = v[1]; Ts[r][c4 + 2] = v[2]; Ts[r][c4 + 3] = v[3];
  }
  __syncthreads();
#pragma unroll
  for (int p = 0; p < 2; ++p) {
    int id = p * 256 + tid;
    int n = id >> 3, k8 = (id & 7) * 8;
    unsigned short tmp[8];
#pragma unroll
    for (int i = 0; i < 8; ++i) tmp[i] = f2bf(Ts[k8 + i][n]);
    *reinterpret_cast<bf16x8*>(&out[(size_t)(n0 + n) * K + k0 + k8]) =
        *reinterpret_cast<bf16x8*>(tmp);
  }
}

// ---------------- QKV GEMM: Xb[4096x1024]bf16 x WqkvT[3072x1024]bf16 ----------------
// 128x128 tile, 4 waves, BK=32, double-buffered global_load_lds both operands,
// XOR chunk swizzle. RoPE epilogue for Q/K; LDS-transpose epilogue for V.
__global__ __launch_bounds__(256) void gemm_qkv_kernel(
    const unsigned short* __restrict__ Xb, const unsigned short* __restrict__ BT,
    unsigned short* __restrict__ Qb, unsigned short* __restrict__ Kb,
    unsigned short* __restrict__ Vtg,
    const float* __restrict__ cost, const float* __restrict__ sint) {
  __shared__ unsigned short As[2][4096];   // [buf][128 rows][32 k], swizzled chunks
  __shared__ unsigned short Bs[2][4096];
  __shared__ unsigned short Vbuf[128][40];

  const int tid = threadIdx.x;
  const int lane = tid & 63;
  const int w = tid >> 6;
  const int lam = lane & 15;
  const int g = lane >> 4;
  const int wr = w >> 1, wc = w & 1;
  const int rowBase = blockIdx.x * 128;
  const int colBase = blockIdx.y * 128;

  f32x4 acc[4][4];
#pragma unroll
  for (int m = 0; m < 4; ++m)
#pragma unroll
    for (int n = 0; n < 4; ++n) acc[m][n] = (f32x4){0.f, 0.f, 0.f, 0.f};

#define GSTAGE(buf, kk0)                                                               \
  {                                                                                    \
    _Pragma("unroll") for (int c = 0; c < 2; ++c) {                                    \
      int ch = c * 256 + w * 64 + lane;                                                \
      int row = ch >> 2, q = ch & 3;                                                   \
      GLOAD16(Xb + (size_t)(rowBase + row) * DMODEL + (kk0) + ((q ^ (row & 3)) * 8),   \
              &As[buf][0] + (c * 256 + w * 64) * 8);                                   \
      GLOAD16(BT + (size_t)(colBase + row) * DMODEL + (kk0) + ((q ^ (row & 3)) * 8),   \
              &Bs[buf][0] + (c * 256 + w * 64) * 8);                                   \
    }                                                                                  \
  }

  GSTAGE(0, 0);
  asm volatile("s_waitcnt vmcnt(0)" ::: "memory");
  __syncthreads();

  int cur = 0;
  for (int kb = 0; kb < 32; ++kb) {
    if (kb < 31) GSTAGE(cur ^ 1, (kb + 1) * 32);
    bf16x8 a[4], b[4];
    const int sw = (g ^ (lam & 3)) * 8;
#pragma unroll
    for (int m = 0; m < 4; ++m)
      a[m] = *reinterpret_cast<bf16x8*>(&As[cur][(wr * 64 + m * 16 + lam) * 32 + sw]);
#pragma unroll
    for (int n = 0; n < 4; ++n)
      b[n] = *reinterpret_cast<bf16x8*>(&Bs[cur][(wc * 64 + n * 16 + lam) * 32 + sw]);
#pragma unroll
    for (int m = 0; m < 4; ++m)
#pragma unroll
      for (int n = 0; n < 4; ++n)
        acc[m][n] = __builtin_amdgcn_mfma_f32_16x16x32_bf16(a[m], b[n], acc[m][n], 0, 0, 0);
    asm volatile("s_waitcnt vmcnt(0)" ::: "memory");
    __syncthreads();
    cur ^= 1;
  }
#undef GSTAGE

  const int mat = blockIdx.y >> 3;   // 0=Q 1=K 2=V (block-uniform)
  if (mat < 2) {
    unsigned short* dst = mat ? Kb : Qb;
    const int h = ((colBase & 1023) + wc * 64) >> 6;
#pragma unroll
    for (int m = 0; m < 4; ++m) {
#pragma unroll
      for (int r = 0; r < 4; ++r) {
        int row = rowBase + wr * 64 + m * 16 + g * 4 + r;
        int bi = row >> 11, t = row & 2047;
        unsigned short* out = &dst[(size_t)((bi * NH + h) * SEQ + t) * DH];
#pragma unroll
        for (int n = 0; n < 2; ++n) {
          int j = n * 16 + lam;
          float c = cost[t * 32 + j], s = sint[t * 32 + j];
          float x0 = acc[m][n][r], x1 = acc[m][n + 2][r];
          out[j] = f2bf(x0 * c - x1 * s);
          out[j + 32] = f2bf(x1 * c + x0 * s);
        }
      }
    }
  } else {
    // V: transpose 128x128 via LDS in 4 chunks of 32 cols -> Vtg[bh][d][t]
    const int b = rowBase >> 11, t0 = rowBase & 2047;
#pragma unroll
    for (int cc = 0; cc < 4; ++cc) {
      __syncthreads();
      if (wc == (cc >> 1)) {
        const int n0 = (cc & 1) * 2;
#pragma unroll
        for (int m = 0; m < 4; ++m)
#pragma unroll
          for (int r = 0; r < 4; ++r)
#pragma unroll
            for (int n2 = 0; n2 < 2; ++n2)
              Vbuf[wr * 64 + m * 16 + g * 4 + r][n2 * 16 + lam] = f2bf(acc[m][n0 + n2][r]);
      }
      __syncthreads();
      const int colq0 = colBase - 2048 + cc * 32;
#pragma unroll
      for (int p2 = 0; p2 < 2; ++p2) {
        int ch = p2 * 256 + tid;
        int d = ch & 31, tq = (ch >> 5) * 8;
        unsigned short tmp[8];
#pragma unroll
        for (int i = 0; i < 8; ++i) tmp[i] = Vbuf[tq + i][d];
        int col = colq0 + d;
        int h = col >> 6, dd = col & 63;
        *reinterpret_cast<bf16x8*>(&Vtg[((size_t)(b * NH + h) * DH + dd) * SEQ + t0 + tq]) =
            *reinterpret_cast<bf16x8*>(tmp);
      }
    }
  }
}

// ---------------- causal flash attention (balanced pairs + KV dbuf) ----------------
__global__ __launch_bounds__(256) void attn_kernel(
    const unsigned short* __restrict__ Qb, const unsigned short* __restrict__ Kb,
    const unsigned short* __restrict__ Vtg, unsigned short* __restrict__ Ob) {
  __shared__ unsigned short Ks[2][4096];   // [buf][64 kv rows][64 d], 16B-chunk XOR swizzle
  __shared__ unsigned short Vs[2][4096];   // [buf][64 d rows][64 kv], same swizzle
  __shared__ unsigned short Ps[4][16][72]; // per-wave P relayout, +8 pad

  const int tid = threadIdx.x;
  const int lane = tid & 63;
  const int w = tid >> 6;
  const int lam = lane & 15;
  const int g = lane >> 4;
  const int p = blockIdx.x;       // 0..15
  const int bh = blockIdx.y;      // 0..31
  const int qtA = p, qtB = 31 - p;

  const unsigned short* kallbase = Kb + (size_t)bh * SEQ * DH;
  const unsigned short* vallbase = Vtg + (size_t)bh * DH * SEQ;

  bf16x8 qa0, qa1;
  f32x4 oacc[4];
  float mrow[4], lrow[4];

#define LOADQ(qt)                                                                     \
  {                                                                                   \
    const unsigned short* qrow = Qb + ((size_t)bh * SEQ + (qt) * 64 + w * 16 + lam) * DH; \
    qa0 = *reinterpret_cast<const bf16x8*>(&qrow[g * 8]);                             \
    qa1 = *reinterpret_cast<const bf16x8*>(&qrow[g * 8 + 32]);                        \
  }
#define RESET_STATE()                                                                 \
  {                                                                                   \
    _Pragma("unroll") for (int f = 0; f < 4; ++f) oacc[f] = (f32x4){0.f, 0.f, 0.f, 0.f}; \
    _Pragma("unroll") for (int r = 0; r < 4; ++r) { mrow[r] = -1e30f; lrow[r] = 0.f; } \
  }
#define STAGE(buf, kt)                                                                \
  {                                                                                   \
    const unsigned short* kb2 = kallbase + (size_t)(kt) * 64 * DH;                    \
    const unsigned short* vb2 = vallbase + (size_t)(kt) * 64;                         \
    _Pragma("unroll") for (int c = 0; c < 2; ++c) {                                   \
      int ch = c * 256 + w * 64 + lane;                                               \
      int row = ch >> 3, q = ch & 7;                                                  \
      GLOAD16(kb2 + row * DH + ((q ^ (row & 7)) * 8),                                 \
              &Ks[buf][0] + (c * 256 + w * 64) * 8);                                  \
      GLOAD16(vb2 + (size_t)row * SEQ + ((q ^ (row & 7)) * 8),                        \
              &Vs[buf][0] + (c * 256 + w * 64) * 8);                                  \
    }                                                                                 \
  }
#define FLUSHO(qt)                                                                    \
  {                                                                                   \
    const int b = bh >> 4, h = bh & 15;                                               \
    _Pragma("unroll") for (int r = 0; r < 4; ++r) {                                   \
      int n = (qt) * 64 + w * 16 + g * 4 + r;                                         \
      float inv = 1.0f / lrow[r];                                                     \
      unsigned short* orow = &Ob[(size_t)(b * SEQ + n) * DMODEL + h * DH];            \
      _Pragma("unroll") for (int f = 0; f < 4; ++f) orow[f * 16 + lam] = f2bf(oacc[f][r] * inv); \
    }                                                                                 \
  }

  RESET_STATE();
  LOADQ(qtA);
  STAGE(0, 0);
  asm volatile("s_waitcnt vmcnt(0)" ::: "memory");
  __syncthreads();

  int cur = 0;
  for (int i = 0; i <= 32; ++i) {
    const int tileB = (i > p);
    const int kt = tileB ? (i - p - 1) : i;
    const int qt = tileB ? qtB : qtA;

    if (i < 32) {
      const int tB2 = (i + 1 > p);
      const int kt2 = tB2 ? (i - p) : (i + 1);
      STAGE(cur ^ 1, kt2);
    }

    f32x4 sacc[4];
#pragma unroll
    for (int f = 0; f < 4; ++f) sacc[f] = (f32x4){0.f, 0.f, 0.f, 0.f};
#pragma unroll
    for (int f = 0; f < 4; ++f) {
      int krow = f * 16 + lam;
      bf16x8 b0 = *reinterpret_cast<bf16x8*>(&Ks[cur][krow * 64 + ((g ^ (krow & 7)) * 8)]);
      bf16x8 b1 = *reinterpret_cast<bf16x8*>(&Ks[cur][krow * 64 + (((g + 4) ^ (krow & 7)) * 8)]);
      sacc[f] = __builtin_amdgcn_mfma_f32_16x16x32_bf16(qa0, b0, sacc[f], 0, 0, 0);
      sacc[f] = __builtin_amdgcn_mfma_f32_16x16x32_bf16(qa1, b1, sacc[f], 0, 0, 0);
    }

    const bool diag = (kt == qt);
    float pexp[4][4];
#pragma unroll
    for (int r = 0; r < 4; ++r) {
      int qi = w * 16 + g * 4 + r;
      float mx = -1e30f;
#pragma unroll
      for (int f = 0; f < 4; ++f) {
        float s = sacc[f][r] * ATT_SCALE;
        if (diag && (f * 16 + lam > qi)) s = -1e30f;
        sacc[f][r] = s;
        mx = fmaxf(mx, s);
      }
      mx = fmaxf(mx, __shfl_xor(mx, 1));
      mx = fmaxf(mx, __shfl_xor(mx, 2));
      mx = fmaxf(mx, __shfl_xor(mx, 4));
      mx = fmaxf(mx, __shfl_xor(mx, 8));
      float mn = fmaxf(mrow[r], mx);
      float alpha = __expf(mrow[r] - mn);
      mrow[r] = mn;
      float sum = 0.f;
#pragma unroll
      for (int f = 0; f < 4; ++f) {
        float pe = __expf(sacc[f][r] - mn);
        pexp[f][r] = pe;
        sum += pe;
      }
      sum += __shfl_xor(sum, 1);
      sum += __shfl_xor(sum, 2);
      sum += __shfl_xor(sum, 4);
      sum += __shfl_xor(sum, 8);
      lrow[r] = lrow[r] * alpha + sum;
#pragma unroll
      for (int f = 0; f < 4; ++f) oacc[f][r] *= alpha;
    }

#pragma unroll
    for (int r = 0; r < 4; ++r) {
      int ii = g * 4 + r;
#pragma unroll
      for (int f = 0; f < 4; ++f) Ps[w][ii][f * 16 + lam] = f2bf(pexp[f][r]);
    }
    bf16x8 pa0 = *reinterpret_cast<bf16x8*>(&Ps[w][lam][g * 8]);
    bf16x8 pa1 = *reinterpret_cast<bf16x8*>(&Ps[w][lam][32 + g * 8]);
#pragma unroll
    for (int f = 0; f < 4; ++f) {
      int vrow = f * 16 + lam;
      bf16x8 vb0 = *reinterpret_cast<bf16x8*>(&Vs[cur][vrow * 64 + ((g ^ (vrow & 7)) * 8)]);
      bf16x8 vb1 = *reinterpret_cast<bf16x8*>(&Vs[cur][vrow * 64 + (((g + 4) ^ (vrow & 7)) * 8)]);
      oacc[f] = __builtin_amdgcn_mfma_f32_16x16x32_bf16(pa0, vb0, oacc[f], 0, 0, 0);
      oacc[f] = __builtin_amdgcn_mfma_f32_16x16x32_bf16(pa1, vb1, oacc[f], 0, 0, 0);
    }

    if (i == p) {
      FLUSHO(qtA);
      RESET_STATE();
      LOADQ(qtB);
    }

    asm volatile("s_waitcnt vmcnt(0)" ::: "memory");
    __syncthreads();
    cur ^= 1;
  }
  FLUSHO(qtB);
#undef LOADQ
#undef RESET_STATE
#undef STAGE
#undef FLUSHO
}

// ------------- output GEMM: Ob[4096x1024]bf16 x WoutT[1024x1024]bf16 -> f32 -------------
__global__ __launch_bounds__(256) void gemm_out_kernel(
    const unsigned short* __restrict__ A, const unsigned short* __restrict__ BT,
    float* __restrict__ C) {
  __shared__ unsigned short As[2][4096];
  __shared__ unsigned short Bs[2][4096];

  const int tid = threadIdx.x;
  const int lane = tid & 63;
  const int w = tid >> 6;
  const int lam = lane & 15;
  const int g = lane >> 4;
  const int wr = w >> 1, wc = w & 1;
  const int rowBase = blockIdx.x * 128;
  const int colBase = blockIdx.y * 128;

  f32x4 acc[4][4];
#pragma unroll
  for (int m = 0; m < 4; ++m)
#pragma unroll
    for (int n = 0; n < 4; ++n) acc[m][n] = (f32x4){0.f, 0.f, 0.f, 0.f};

#define GSTAGE(buf, kk0)                                                               \
  {                                                                                    \
    _Pragma("unroll") for (int c = 0; c < 2; ++c) {                                    \
      int ch = c * 256 + w * 64 + lane;                                                \
      int row = ch >> 2, q = ch & 3;                                                   \
      GLOAD16(A + (size_t)(rowBase + row) * DMODEL + (kk0) + ((q ^ (row & 3)) * 8),    \
              &As[buf][0] + (c * 256 + w * 64) * 8);                                   \
      GLOAD16(BT + (size_t)(colBase + row) * DMODEL + (kk0) + ((q ^ (row & 3)) * 8),   \
              &Bs[buf][0] + (c * 256 + w * 64) * 8);                                   \
    }                                                                                  \
  }

  GSTAGE(0, 0);
  asm volatile("s_waitcnt vmcnt(0)" ::: "memory");
  __syncthreads();

  int cur = 0;
  for (int kb = 0; kb < 32; ++kb) {
    if (kb < 31) GSTAGE(cur ^ 1, (kb + 1) * 32);
    bf16x8 a[4], b[4];
    const int sw = (g ^ (lam & 3)) * 8;
#pragma unroll
    for (int m = 0; m < 4; ++m)
      a[m] = *reinterpret_cast<bf16x8*>(&As[cur][(wr * 64 + m * 16 + lam) * 32 + sw]);
#pragma unroll
    for (int n = 0; n < 4; ++n)
      b[n] = *reinterpret_cast<bf16x8*>(&Bs[cur][(wc * 64 + n * 16 + lam) * 32 + sw]);
#pragma unroll
    for (int m = 0; m < 4; ++m)
#pragma unroll
      for (int n = 0; n < 4; ++n)
        acc[m][n] = __builtin_amdgcn_mfma_f32_16x16x32_bf16(a[m], b[n], acc[m][n], 0, 0, 0);
    asm volatile("s_waitcnt vmcnt(0)" ::: "memory");
    __syncthreads();
    cur ^= 1;
  }
#undef GSTAGE

#pragma unroll
  for (int m = 0; m < 4; ++m)
#pragma unroll
    for (int r = 0; r < 4; ++r) {
      int row = rowBase + wr * 64 + m * 16 + g * 4 + r;
#pragma unroll
      for (int n = 0; n < 4; ++n)
        C[(size_t)row * DMODEL + colBase + wc * 64 + n * 16 + lam] = acc[m][n][r];
    }
}

extern "C" void kernel_launch(void* const* d_in, const int* in_sizes, int n_in,
                              void* d_out, int out_size, void* d_ws, size_t ws_size,
                              hipStream_t stream) {
  const float* x = (const float*)d_in[0];       // [2][2048][1024]
  const float* w_qkv = (const float*)d_in[1];   // [1024][3072]
  const float* w_out = (const float*)d_in[2];   // [1024][1024]
  float* out = (float*)d_out;

  char* ws = (char*)d_ws;
  const size_t MB = 1024 * 1024;
  unsigned short* WqkvT = (unsigned short*)(ws);             // 6MB  [phase1]
  float* cost = (float*)(ws + 6 * MB);                       // tables [phase1]
  float* sint = cost + SEQ * 32;
  unsigned short* Ob = (unsigned short*)(ws);                // 8MB  [after attn]
  unsigned short* WoutT = (unsigned short*)(ws + 8 * MB);    // 2MB
  unsigned short* Qb = (unsigned short*)(ws + 10 * MB);      // 8MB
  unsigned short* Kb = (unsigned short*)(ws + 18 * MB);      // 8MB
  unsigned short* Vtg = (unsigned short*)(ws + 26 * MB);     // 8MB   [bh][d][t]
  unsigned short* Xb = (unsigned short*)d_out;               // 8MB scratch in d_out;
                                                             // fully overwritten by gemm_out

  rope_tables_kernel<<<SEQ * 32 / 256, 256, 0, stream>>>(cost, sint);
  x2bf_kernel<<<2048, 256, 0, stream>>>(x, Xb);
  transw_kernel<<<dim3(16, 48), 256, 0, stream>>>(w_qkv, WqkvT, DMODEL, NQKV);
  transw_kernel<<<dim3(16, 16), 256, 0, stream>>>(w_out, WoutT, DMODEL, DMODEL);
  gemm_qkv_kernel<<<dim3(32, 24), 256, 0, stream>>>(Xb, WqkvT, Qb, Kb, Vtg, cost, sint);
  attn_kernel<<<dim3(16, 32), 256, 0, stream>>>(Qb, Kb, Vtg, Ob);
  gemm_out_kernel<<<dim3(32, 8), 256, 0, stream>>>(Ob, WoutT, out);
}

// Round 4
// 147.587 us; speedup vs baseline: 1.9660x; 1.1439x over previous
//
#include <hip/hip_runtime.h>

#define SEQ 2048
#define NH 16
#define DH 64
#define DMODEL 1024
#define NQKV 3072

typedef __attribute__((ext_vector_type(8))) short bf16x8;
typedef __attribute__((ext_vector_type(4))) short bf16x4;
typedef __attribute__((ext_vector_type(4))) float f32x4;

#define GLOAD16(src, dst)                                                              \
  __builtin_amdgcn_global_load_lds((const __attribute__((address_space(1))) void*)(src), \
                                   (__attribute__((address_space(3))) void*)(dst), 16, 0, 0)

__device__ __forceinline__ unsigned short f2bf(float f) {
  union { float f; unsigned u; } v; v.f = f;
  unsigned r = v.u + 0x7FFFu + ((v.u >> 16) & 1u);
  return (unsigned short)(r >> 16);
}

__device__ __forceinline__ unsigned pkbf(float a, float b) {
  unsigned r;
  asm("v_cvt_pk_bf16_f32 %0, %1, %2" : "=v"(r) : "v"(a), "v"(b));
  return r;
}

// ---------------- RoPE tables: cost/sint [SEQ][32] fp32 ----------------
__global__ void rope_tables_kernel(float* __restrict__ cost, float* __restrict__ sint) {
  int idx = blockIdx.x * blockDim.x + threadIdx.x;
  int t = idx >> 5, j = idx & 31;
  float inv = powf(10000.0f, -(float)(2 * j) / 64.0f);
  float a = (float)t * inv;
  cost[idx] = cosf(a);
  sint[idx] = sinf(a);
}

// ---------------- X fp32 -> bf16 (into d_out scratch) ----------------
__global__ __launch_bounds__(256) void x2bf_kernel(const float* __restrict__ in,
                                                   unsigned short* __restrict__ out) {
  int idx = blockIdx.x * 256 + threadIdx.x;
  const f32x4 v0 = *reinterpret_cast<const f32x4*>(&in[(size_t)idx * 8]);
  const f32x4 v1 = *reinterpret_cast<const f32x4*>(&in[(size_t)idx * 8 + 4]);
  bf16x8 o;
  o[0] = (short)f2bf(v0[0]); o[1] = (short)f2bf(v0[1]);
  o[2] = (short)f2bf(v0[2]); o[3] = (short)f2bf(v0[3]);
  o[4] = (short)f2bf(v1[0]); o[5] = (short)f2bf(v1[1]);
  o[6] = (short)f2bf(v1[2]); o[7] = (short)f2bf(v1[3]);
  *reinterpret_cast<bf16x8*>(&out[(size_t)idx * 8]) = o;
}

// ------- transpose+convert: in f32 [K][N] -> out bf16 [N][K], 64x64 tiles -------
__global__ __launch_bounds__(256) void transw_kernel(const float* __restrict__ in,
                                                     unsigned short* __restrict__ out,
                                                     int K, int N) {
  __shared__ float Ts[64][65];
  const int tid = threadIdx.x;
  const int k0 = blockIdx.x * 64, n0 = blockIdx.y * 64;
#pragma unroll
  for (int p = 0; p < 4; ++p) {
    int id = p * 256 + tid;
    int r = id >> 4, c4 = (id & 15) * 4;
    const f32x4 v = *reinterpret_cast<const f32x4*>(&in[(size_t)(k0 + r) * N + n0 + c4]);
    Ts[r][c4] = v[0]; Ts[r][c4 + 1] = v[1]; Ts[r][c4 + 2] = v[2]; Ts[r][c4 + 3] = v[3];
  }
  __syncthreads();
#pragma unroll
  for (int p = 0; p < 2; ++p) {
    int id = p * 256 + tid;
    int n = id >> 3, k8 = (id & 7) * 8;
    unsigned short tmp[8];
#pragma unroll
    for (int i = 0; i < 8; ++i) tmp[i] = f2bf(Ts[k8 + i][n]);
    *reinterpret_cast<bf16x8*>(&out[(size_t)(n0 + n) * K + k0 + k8]) =
        *reinterpret_cast<bf16x8*>(tmp);
  }
}

// ---------------- QKV GEMM: Xb[4096x1024]bf16 x WqkvT[3072x1024]bf16 ----------------
__global__ __launch_bounds__(256) void gemm_qkv_kernel(
    const unsigned short* __restrict__ Xb, const unsigned short* __restrict__ BT,
    unsigned short* __restrict__ Qb, unsigned short* __restrict__ Kb,
    unsigned short* __restrict__ Vtg,
    const float* __restrict__ cost, const float* __restrict__ sint) {
  __shared__ unsigned short As[2][4096];
  __shared__ unsigned short Bs[2][4096];
  __shared__ unsigned short Vbuf[128][40];

  const int tid = threadIdx.x;
  const int lane = tid & 63;
  const int w = tid >> 6;
  const int lam = lane & 15;
  const int g = lane >> 4;
  const int wr = w >> 1, wc = w & 1;
  const int rowBase = blockIdx.x * 128;
  const int colBase = blockIdx.y * 128;

  f32x4 acc[4][4];
#pragma unroll
  for (int m = 0; m < 4; ++m)
#pragma unroll
    for (int n = 0; n < 4; ++n) acc[m][n] = (f32x4){0.f, 0.f, 0.f, 0.f};

#define GSTAGE(buf, kk0)                                                               \
  {                                                                                    \
    _Pragma("unroll") for (int c = 0; c < 2; ++c) {                                    \
      int ch = c * 256 + w * 64 + lane;                                                \
      int row = ch >> 2, q = ch & 3;                                                   \
      GLOAD16(Xb + (size_t)(rowBase + row) * DMODEL + (kk0) + ((q ^ (row & 3)) * 8),   \
              &As[buf][0] + (c * 256 + w * 64) * 8);                                   \
      GLOAD16(BT + (size_t)(colBase + row) * DMODEL + (kk0) + ((q ^ (row & 3)) * 8),   \
              &Bs[buf][0] + (c * 256 + w * 64) * 8);                                   \
    }                                                                                  \
  }

  GSTAGE(0, 0);
  asm volatile("s_waitcnt vmcnt(0)" ::: "memory");
  __syncthreads();

  int cur = 0;
  for (int kb = 0; kb < 32; ++kb) {
    if (kb < 31) GSTAGE(cur ^ 1, (kb + 1) * 32);
    bf16x8 a[4], b[4];
    const int sw = (g ^ (lam & 3)) * 8;
#pragma unroll
    for (int m = 0; m < 4; ++m)
      a[m] = *reinterpret_cast<bf16x8*>(&As[cur][(wr * 64 + m * 16 + lam) * 32 + sw]);
#pragma unroll
    for (int n = 0; n < 4; ++n)
      b[n] = *reinterpret_cast<bf16x8*>(&Bs[cur][(wc * 64 + n * 16 + lam) * 32 + sw]);
    __builtin_amdgcn_s_setprio(1);
#pragma unroll
    for (int m = 0; m < 4; ++m)
#pragma unroll
      for (int n = 0; n < 4; ++n)
        acc[m][n] = __builtin_amdgcn_mfma_f32_16x16x32_bf16(a[m], b[n], acc[m][n], 0, 0, 0);
    __builtin_amdgcn_s_setprio(0);
    asm volatile("s_waitcnt vmcnt(0)" ::: "memory");
    __syncthreads();
    cur ^= 1;
  }
#undef GSTAGE

  const int mat = blockIdx.y >> 3;   // 0=Q 1=K 2=V (block-uniform)
  if (mat < 2) {
    unsigned short* dst = mat ? Kb : Qb;
    const float sc = mat ? 1.0f : 0.125f;    // fold attention scale into Q
    const int h = ((colBase & 1023) + wc * 64) >> 6;
#pragma unroll
    for (int m = 0; m < 4; ++m) {
#pragma unroll
      for (int r = 0; r < 4; ++r) {
        int row = rowBase + wr * 64 + m * 16 + g * 4 + r;
        int bi = row >> 11, t = row & 2047;
        unsigned short* out = &dst[(size_t)((bi * NH + h) * SEQ + t) * DH];
#pragma unroll
        for (int n = 0; n < 2; ++n) {
          int j = n * 16 + lam;
          float c = cost[t * 32 + j], s = sint[t * 32 + j];
          float x0 = acc[m][n][r], x1 = acc[m][n + 2][r];
          out[j] = f2bf((x0 * c - x1 * s) * sc);
          out[j + 32] = f2bf((x1 * c + x0 * s) * sc);
        }
      }
    }
  } else {
    // V: transpose 128x128 via LDS in 4 chunks of 32 cols -> Vtg[bh][d][t]
    const int b = rowBase >> 11, t0 = rowBase & 2047;
#pragma unroll
    for (int cc = 0; cc < 4; ++cc) {
      __syncthreads();
      if (wc == (cc >> 1)) {
        const int n0 = (cc & 1) * 2;
#pragma unroll
        for (int m = 0; m < 4; ++m)
#pragma unroll
          for (int r = 0; r < 4; ++r)
#pragma unroll
            for (int n2 = 0; n2 < 2; ++n2)
              Vbuf[wr * 64 + m * 16 + g * 4 + r][n2 * 16 + lam] = f2bf(acc[m][n0 + n2][r]);
      }
      __syncthreads();
      const int colq0 = colBase - 2048 + cc * 32;
#pragma unroll
      for (int p2 = 0; p2 < 2; ++p2) {
        int ch = p2 * 256 + tid;
        int d = ch & 31, tq = (ch >> 5) * 8;
        unsigned short tmp[8];
#pragma unroll
        for (int i = 0; i < 8; ++i) tmp[i] = Vbuf[tq + i][d];
        int col = colq0 + d;
        int h = col >> 6, dd = col & 63;
        *reinterpret_cast<bf16x8*>(&Vtg[((size_t)(b * NH + h) * DH + dd) * SEQ + t0 + tq]) =
            *reinterpret_cast<bf16x8*>(tmp);
      }
    }
  }
}

// ---------------- causal flash attention: swapped QK^T, scalar m/l state ----------------
// grid (32 bh, 16 pair): same-bh blocks share an XCD L2 (id%8 = bh%8).
__global__ __launch_bounds__(256) void attn_kernel(
    const unsigned short* __restrict__ Qb, const unsigned short* __restrict__ Kb,
    const unsigned short* __restrict__ Vtg, unsigned short* __restrict__ Ob) {
  __shared__ unsigned short Ks[2][4096];   // [buf][64 kv][64 d], 16B-chunk XOR swizzle
  __shared__ unsigned short Vs[2][4096];   // [buf][64 d][64 kv], same swizzle
  __shared__ unsigned short Ps[4][1024];   // per-wave [16 q][64 kv], swizzled

  const int tid = threadIdx.x;
  const int lane = tid & 63;
  const int w = tid >> 6;
  const int lam = lane & 15;
  const int g = lane >> 4;
  const int bh = blockIdx.x;      // 0..31
  const int p = blockIdx.y;       // 0..15
  const int qtA = p, qtB = 31 - p;
  const int ql = w * 16 + lam;    // q row within 64-tile

  const unsigned short* kallbase = Kb + (size_t)bh * SEQ * DH;
  const unsigned short* vallbase = Vtg + (size_t)bh * DH * SEQ;

  bf16x8 qb0, qb1;
  f32x4 oacc[4];
  float mr, lr;

#define LOADQ(qt)                                                                     \
  {                                                                                   \
    const unsigned short* qrow = Qb + ((size_t)bh * SEQ + (qt) * 64 + w * 16 + lam) * DH; \
    qb0 = *reinterpret_cast<const bf16x8*>(&qrow[g * 8]);                             \
    qb1 = *reinterpret_cast<const bf16x8*>(&qrow[g * 8 + 32]);                        \
  }
#define RESET_STATE()                                                                 \
  {                                                                                   \
    _Pragma("unroll") for (int f = 0; f < 4; ++f) oacc[f] = (f32x4){0.f, 0.f, 0.f, 0.f}; \
    mr = -1e30f; lr = 0.f;                                                            \
  }
#define STAGE(buf, kt)                                                                \
  {                                                                                   \
    const unsigned short* kb2 = kallbase + (size_t)(kt) * 64 * DH;                    \
    const unsigned short* vb2 = vallbase + (size_t)(kt) * 64;                         \
    _Pragma("unroll") for (int c = 0; c < 2; ++c) {                                   \
      int ch = c * 256 + w * 64 + lane;                                               \
      int row = ch >> 3, q = ch & 7;                                                  \
      GLOAD16(kb2 + row * DH + ((q ^ (row & 7)) * 8),                                 \
              &Ks[buf][0] + (c * 256 + w * 64) * 8);                                  \
      GLOAD16(vb2 + (size_t)row * SEQ + ((q ^ (row & 7)) * 8),                        \
              &Vs[buf][0] + (c * 256 + w * 64) * 8);                                  \
    }                                                                                 \
  }
#define FLUSHO(qt)                                                                    \
  {                                                                                   \
    const int b = bh >> 4, h = bh & 15;                                               \
    float rinv = 1.0f / lr;                                                           \
    _Pragma("unroll") for (int r = 0; r < 4; ++r) {                                   \
      int n = (qt) * 64 + w * 16 + g * 4 + r;                                         \
      float inv = __shfl(rinv, g * 4 + r);                                            \
      unsigned short* orow = &Ob[(size_t)(b * SEQ + n) * DMODEL + h * DH];            \
      _Pragma("unroll") for (int f = 0; f < 4; ++f) orow[f * 16 + lam] = f2bf(oacc[f][r] * inv); \
    }                                                                                 \
  }

  RESET_STATE();
  LOADQ(qtA);
  STAGE(0, 0);
  asm volatile("s_waitcnt vmcnt(0)" ::: "memory");
  __syncthreads();

  int cur = 0;
  for (int i = 0; i <= 32; ++i) {
    const int tileB = (i > p);
    const int kt = tileB ? (i - p - 1) : i;
    const int qt = tileB ? qtB : qtA;

    if (i < 32) {
      const int tB2 = (i + 1 > p);
      const int kt2 = tB2 ? (i - p) : (i + 1);
      STAGE(cur ^ 1, kt2);
    }

    // ---- S^T = K Q^T : sacc[f][r] = S[kv=16f+4g+r][q=lam] ----
    f32x4 sacc[4];
#pragma unroll
    for (int f = 0; f < 4; ++f) sacc[f] = (f32x4){0.f, 0.f, 0.f, 0.f};
    __builtin_amdgcn_s_setprio(1);
#pragma unroll
    for (int f = 0; f < 4; ++f) {
      int krow = f * 16 + lam;
      bf16x8 k0 = *reinterpret_cast<bf16x8*>(&Ks[cur][krow * 64 + ((g ^ (krow & 7)) * 8)]);
      bf16x8 k1 = *reinterpret_cast<bf16x8*>(&Ks[cur][krow * 64 + (((g + 4) ^ (krow & 7)) * 8)]);
      sacc[f] = __builtin_amdgcn_mfma_f32_16x16x32_bf16(k0, qb0, sacc[f], 0, 0, 0);
      sacc[f] = __builtin_amdgcn_mfma_f32_16x16x32_bf16(k1, qb1, sacc[f], 0, 0, 0);
    }
    __builtin_amdgcn_s_setprio(0);

    if (kt == qt) {  // causal mask, diag tile only (block-uniform branch)
#pragma unroll
      for (int f = 0; f < 4; ++f)
#pragma unroll
        for (int r = 0; r < 4; ++r)
          if (f * 16 + g * 4 + r > ql) sacc[f][r] = -1e30f;
    }

    // ---- online softmax: row q=lam is in-lane (16 vals) + 2 shfl over g ----
    float mx = fmaxf(fmaxf(fmaxf(sacc[0][0], sacc[0][1]), fmaxf(sacc[0][2], sacc[0][3])),
                     fmaxf(fmaxf(sacc[1][0], sacc[1][1]), fmaxf(sacc[1][2], sacc[1][3])));
    mx = fmaxf(mx, fmaxf(fmaxf(fmaxf(sacc[2][0], sacc[2][1]), fmaxf(sacc[2][2], sacc[2][3])),
                         fmaxf(fmaxf(sacc[3][0], sacc[3][1]), fmaxf(sacc[3][2], sacc[3][3]))));
    mx = fmaxf(mx, __shfl_xor(mx, 16));
    mx = fmaxf(mx, __shfl_xor(mx, 32));
    float mn = fmaxf(mr, mx);
    float alpha = __expf(mr - mn);
    mr = mn;

    float pv[4][4];
    float sum = 0.f;
#pragma unroll
    for (int f = 0; f < 4; ++f)
#pragma unroll
      for (int r = 0; r < 4; ++r) {
        pv[f][r] = __expf(sacc[f][r] - mn);
        sum += pv[f][r];
      }
    sum += __shfl_xor(sum, 16);
    sum += __shfl_xor(sum, 32);
    lr = lr * alpha + sum;

    // rescale O (D-layout rows q=g*4+r) with alpha broadcast from lane q
#pragma unroll
    for (int r = 0; r < 4; ++r) {
      float af = __shfl(alpha, g * 4 + r);
#pragma unroll
      for (int f = 0; f < 4; ++f) oacc[f][r] *= af;
    }

    // ---- pack P -> Ps[w][q=lam][kv], swizzled, 4x ds_write_b64 ----
#pragma unroll
    for (int f = 0; f < 4; ++f) {
      unsigned w0 = pkbf(pv[f][0], pv[f][1]);
      unsigned w1 = pkbf(pv[f][2], pv[f][3]);
      int chunk = 2 * f + (g >> 1);
      int addr = lam * 64 + ((chunk ^ (lam & 7)) << 3) + ((g & 1) << 2);
      uint2 u; u.x = w0; u.y = w1;
      *reinterpret_cast<uint2*>(&Ps[w][addr]) = u;
    }
    bf16x8 pa0 = *reinterpret_cast<bf16x8*>(&Ps[w][lam * 64 + ((g ^ (lam & 7)) << 3)]);
    bf16x8 pa1 = *reinterpret_cast<bf16x8*>(&Ps[w][lam * 64 + (((4 + g) ^ (lam & 7)) << 3)]);

    __builtin_amdgcn_s_setprio(1);
#pragma unroll
    for (int f = 0; f < 4; ++f) {
      int vrow = f * 16 + lam;
      bf16x8 vb0 = *reinterpret_cast<bf16x8*>(&Vs[cur][vrow * 64 + ((g ^ (vrow & 7)) * 8)]);
      bf16x8 vb1 = *reinterpret_cast<bf16x8*>(&Vs[cur][vrow * 64 + (((g + 4) ^ (vrow & 7)) * 8)]);
      oacc[f] = __builtin_amdgcn_mfma_f32_16x16x32_bf16(pa0, vb0, oacc[f], 0, 0, 0);
      oacc[f] = __builtin_amdgcn_mfma_f32_16x16x32_bf16(pa1, vb1, oacc[f], 0, 0, 0);
    }
    __builtin_amdgcn_s_setprio(0);

    if (i == p) {
      FLUSHO(qtA);
      RESET_STATE();
      LOADQ(qtB);
    }

    asm volatile("s_waitcnt vmcnt(0)" ::: "memory");
    __syncthreads();
    cur ^= 1;
  }
  FLUSHO(qtB);
#undef LOADQ
#undef RESET_STATE
#undef STAGE
#undef FLUSHO
}

// ------------- output GEMM: Ob[4096x1024]bf16 x WoutT[1024x1024]bf16 -> f32 -------------
__global__ __launch_bounds__(256) void gemm_out_kernel(
    const unsigned short* __restrict__ A, const unsigned short* __restrict__ BT,
    float* __restrict__ C) {
  __shared__ unsigned short As[2][4096];
  __shared__ unsigned short Bs[2][4096];

  const int tid = threadIdx.x;
  const int lane = tid & 63;
  const int w = tid >> 6;
  const int lam = lane & 15;
  const int g = lane >> 4;
  const int wr = w >> 1, wc = w & 1;
  const int rowBase = blockIdx.x * 128;
  const int colBase = blockIdx.y * 128;

  f32x4 acc[4][4];
#pragma unroll
  for (int m = 0; m < 4; ++m)
#pragma unroll
    for (int n = 0; n < 4; ++n) acc[m][n] = (f32x4){0.f, 0.f, 0.f, 0.f};

#define GSTAGE(buf, kk0)                                                               \
  {                                                                                    \
    _Pragma("unroll") for (int c = 0; c < 2; ++c) {                                    \
      int ch = c * 256 + w * 64 + lane;                                                \
      int row = ch >> 2, q = ch & 3;                                                   \
      GLOAD16(A + (size_t)(rowBase + row) * DMODEL + (kk0) + ((q ^ (row & 3)) * 8),    \
              &As[buf][0] + (c * 256 + w * 64) * 8);                                   \
      GLOAD16(BT + (size_t)(colBase + row) * DMODEL + (kk0) + ((q ^ (row & 3)) * 8),   \
              &Bs[buf][0] + (c * 256 + w * 64) * 8);                                   \
    }                                                                                  \
  }

  GSTAGE(0, 0);
  asm volatile("s_waitcnt vmcnt(0)" ::: "memory");
  __syncthreads();

  int cur = 0;
  for (int kb = 0; kb < 32; ++kb) {
    if (kb < 31) GSTAGE(cur ^ 1, (kb + 1) * 32);
    bf16x8 a[4], b[4];
    const int sw = (g ^ (lam & 3)) * 8;
#pragma unroll
    for (int m = 0; m < 4; ++m)
      a[m] = *reinterpret_cast<bf16x8*>(&As[cur][(wr * 64 + m * 16 + lam) * 32 + sw]);
#pragma unroll
    for (int n = 0; n < 4; ++n)
      b[n] = *reinterpret_cast<bf16x8*>(&Bs[cur][(wc * 64 + n * 16 + lam) * 32 + sw]);
    __builtin_amdgcn_s_setprio(1);
#pragma unroll
    for (int m = 0; m < 4; ++m)
#pragma unroll
      for (int n = 0; n < 4; ++n)
        acc[m][n] = __builtin_amdgcn_mfma_f32_16x16x32_bf16(a[m], b[n], acc[m][n], 0, 0, 0);
    __builtin_amdgcn_s_setprio(0);
    asm volatile("s_waitcnt vmcnt(0)" ::: "memory");
    __syncthreads();
    cur ^= 1;
  }
#undef GSTAGE

#pragma unroll
  for (int m = 0; m < 4; ++m)
#pragma unroll
    for (int r = 0; r < 4; ++r) {
      int row = rowBase + wr * 64 + m * 16 + g * 4 + r;
#pragma unroll
      for (int n = 0; n < 4; ++n)
        C[(size_t)row * DMODEL + colBase + wc * 64 + n * 16 + lam] = acc[m][n][r];
    }
}

extern "C" void kernel_launch(void* const* d_in, const int* in_sizes, int n_in,
                              void* d_out, int out_size, void* d_ws, size_t ws_size,
                              hipStream_t stream) {
  const float* x = (const float*)d_in[0];       // [2][2048][1024]
  const float* w_qkv = (const float*)d_in[1];   // [1024][3072]
  const float* w_out = (const float*)d_in[2];   // [1024][1024]
  float* out = (float*)d_out;

  char* ws = (char*)d_ws;
  const size_t MB = 1024 * 1024;
  unsigned short* WqkvT = (unsigned short*)(ws);             // 6MB  [phase1]
  float* cost = (float*)(ws + 6 * MB);
  float* sint = cost + SEQ * 32;
  unsigned short* Ob = (unsigned short*)(ws);                // 8MB  [after attn]
  unsigned short* WoutT = (unsigned short*)(ws + 8 * MB);    // 2MB
  unsigned short* Qb = (unsigned short*)(ws + 10 * MB);      // 8MB
  unsigned short* Kb = (unsigned short*)(ws + 18 * MB);      // 8MB
  unsigned short* Vtg = (unsigned short*)(ws + 26 * MB);     // 8MB   [bh][d][t]
  unsigned short* Xb = (unsigned short*)d_out;               // scratch; overwritten by gemm_out

  rope_tables_kernel<<<SEQ * 32 / 256, 256, 0, stream>>>(cost, sint);
  x2bf_kernel<<<2048, 256, 0, stream>>>(x, Xb);
  transw_kernel<<<dim3(16, 48), 256, 0, stream>>>(w_qkv, WqkvT, DMODEL, NQKV);
  transw_kernel<<<dim3(16, 16), 256, 0, stream>>>(w_out, WoutT, DMODEL, DMODEL);
  gemm_qkv_kernel<<<dim3(32, 24), 256, 0, stream>>>(Xb, WqkvT, Qb, Kb, Vtg, cost, sint);
  attn_kernel<<<dim3(32, 16), 256, 0, stream>>>(Qb, Kb, Vtg, Ob);
  gemm_out_kernel<<<dim3(32, 8), 256, 0, stream>>>(Ob, WoutT, out);
}

// Round 5
// 133.023 us; speedup vs baseline: 2.1812x; 1.1095x over previous
//
#include <hip/hip_runtime.h>

#define SEQ 2048
#define NH 16
#define DH 64
#define DMODEL 1024
#define NQKV 3072

typedef __attribute__((ext_vector_type(8))) short bf16x8;
typedef __attribute__((ext_vector_type(4))) short bf16x4;
typedef __attribute__((ext_vector_type(4))) float f32x4;

#define GLOAD16(src, dst)                                                              \
  __builtin_amdgcn_global_load_lds((const __attribute__((address_space(1))) void*)(src), \
                                   (__attribute__((address_space(3))) void*)(dst), 16, 0, 0)

__device__ __forceinline__ unsigned short f2bf(float f) {
  union { float f; unsigned u; } v; v.f = f;
  unsigned r = v.u + 0x7FFFu + ((v.u >> 16) & 1u);
  return (unsigned short)(r >> 16);
}

__device__ __forceinline__ unsigned pkbf(float a, float b) {
  unsigned r;
  asm("v_cvt_pk_bf16_f32 %0, %1, %2" : "=v"(r) : "v"(a), "v"(b));
  return r;
}

// ---------------- fused prep: x->bf16, two weight transposes, rope tables ----------------
__device__ __forceinline__ void transw_body(const float* __restrict__ in,
                                            unsigned short* __restrict__ out,
                                            int K, int N, int k0, int n0, int tid,
                                            float (*Ts)[65]) {
#pragma unroll
  for (int p = 0; p < 4; ++p) {
    int id = p * 256 + tid;
    int r = id >> 4, c4 = (id & 15) * 4;
    const f32x4 v = *reinterpret_cast<const f32x4*>(&in[(size_t)(k0 + r) * N + n0 + c4]);
    Ts[r][c4] = v[0]; Ts[r][c4 + 1] = v[1]; Ts[r][c4 + 2] = v[2]; Ts[r][c4 + 3] = v[3];
  }
  __syncthreads();
#pragma unroll
  for (int p = 0; p < 2; ++p) {
    int id = p * 256 + tid;
    int n = id >> 3, k8 = (id & 7) * 8;
    unsigned short tmp[8];
#pragma unroll
    for (int i = 0; i < 8; ++i) tmp[i] = f2bf(Ts[k8 + i][n]);
    *reinterpret_cast<bf16x8*>(&out[(size_t)(n0 + n) * K + k0 + k8]) =
        *reinterpret_cast<bf16x8*>(tmp);
  }
}

__global__ __launch_bounds__(256) void prep_kernel(
    const float* __restrict__ x, const float* __restrict__ w_qkv,
    const float* __restrict__ w_out, unsigned short* __restrict__ Xb,
    unsigned short* __restrict__ WqkvT, unsigned short* __restrict__ WoutT,
    float* __restrict__ cost, float* __restrict__ sint) {
  __shared__ float Ts[64][65];
  const int tid = threadIdx.x;
  const int id = blockIdx.x;
  if (id < 2048) {                       // x fp32 -> bf16
    int idx = id * 256 + tid;
    const f32x4 v0 = *reinterpret_cast<const f32x4*>(&x[(size_t)idx * 8]);
    const f32x4 v1 = *reinterpret_cast<const f32x4*>(&x[(size_t)idx * 8 + 4]);
    bf16x8 o;
    o[0] = (short)f2bf(v0[0]); o[1] = (short)f2bf(v0[1]);
    o[2] = (short)f2bf(v0[2]); o[3] = (short)f2bf(v0[3]);
    o[4] = (short)f2bf(v1[0]); o[5] = (short)f2bf(v1[1]);
    o[6] = (short)f2bf(v1[2]); o[7] = (short)f2bf(v1[3]);
    *reinterpret_cast<bf16x8*>(&Xb[(size_t)idx * 8]) = o;
  } else if (id < 2816) {                // w_qkv [1024][3072] -> WqkvT [3072][1024]
    int t = id - 2048;
    transw_body(w_qkv, WqkvT, DMODEL, NQKV, (t & 15) * 64, (t >> 4) * 64, tid, Ts);
  } else if (id < 3072) {                // w_out -> WoutT
    int t = id - 2816;
    transw_body(w_out, WoutT, DMODEL, DMODEL, (t & 15) * 64, (t >> 4) * 64, tid, Ts);
  } else {                               // rope tables
    int idx = (id - 3072) * 256 + tid;
    int t = idx >> 5, j = idx & 31;
    float inv = powf(10000.0f, -(float)(2 * j) / 64.0f);
    float a = (float)t * inv;
    cost[idx] = cosf(a);
    sint[idx] = sinf(a);
  }
}

// ---------------- QKV GEMM: 3-deep counted-vmcnt pipeline ----------------
__global__ __launch_bounds__(256) void gemm_qkv_kernel(
    const unsigned short* __restrict__ Xb, const unsigned short* __restrict__ BT,
    unsigned short* __restrict__ Qb, unsigned short* __restrict__ Kb,
    unsigned short* __restrict__ Vtg,
    const float* __restrict__ cost, const float* __restrict__ sint) {
  __shared__ unsigned short As[3][4096];
  __shared__ unsigned short Bs[3][4096];

  const int tid = threadIdx.x;
  const int lane = tid & 63;
  const int w = tid >> 6;
  const int lam = lane & 15;
  const int g = lane >> 4;
  const int wr = w >> 1, wc = w & 1;
  const int rowBase = blockIdx.x * 128;
  const int colBase = blockIdx.y * 128;

  f32x4 acc[4][4];
#pragma unroll
  for (int m = 0; m < 4; ++m)
#pragma unroll
    for (int n = 0; n < 4; ++n) acc[m][n] = (f32x4){0.f, 0.f, 0.f, 0.f};

#define GSTAGE(buf, kk0)                                                               \
  {                                                                                    \
    _Pragma("unroll") for (int c = 0; c < 2; ++c) {                                    \
      int ch = c * 256 + w * 64 + lane;                                                \
      int row = ch >> 2, q = ch & 3;                                                   \
      GLOAD16(Xb + (size_t)(rowBase + row) * DMODEL + (kk0) + ((q ^ (row & 3)) * 8),   \
              &As[buf][0] + (c * 256 + w * 64) * 8);                                   \
      GLOAD16(BT + (size_t)(colBase + row) * DMODEL + (kk0) + ((q ^ (row & 3)) * 8),   \
              &Bs[buf][0] + (c * 256 + w * 64) * 8);                                   \
    }                                                                                  \
  }

  GSTAGE(0, 0);
  GSTAGE(1, 32);

  for (int kb = 0; kb < 32; ++kb) {
    if (kb + 2 < 32) {
      GSTAGE((kb + 2) % 3, (kb + 2) * 32);
      asm volatile("s_waitcnt vmcnt(8)" ::: "memory");
    } else if (kb + 1 < 32) {
      asm volatile("s_waitcnt vmcnt(4)" ::: "memory");
    } else {
      asm volatile("s_waitcnt vmcnt(0)" ::: "memory");
    }
    __builtin_amdgcn_s_barrier();            // buf kb published
    const int cb = kb % 3;
    bf16x8 a[4], b[4];
    const int sw = (g ^ (lam & 3)) * 8;
#pragma unroll
    for (int m = 0; m < 4; ++m)
      a[m] = *reinterpret_cast<bf16x8*>(&As[cb][(wr * 64 + m * 16 + lam) * 32 + sw]);
#pragma unroll
    for (int n = 0; n < 4; ++n)
      b[n] = *reinterpret_cast<bf16x8*>(&Bs[cb][(wc * 64 + n * 16 + lam) * 32 + sw]);
    __builtin_amdgcn_s_setprio(1);
#pragma unroll
    for (int m = 0; m < 4; ++m)
#pragma unroll
      for (int n = 0; n < 4; ++n)
        acc[m][n] = __builtin_amdgcn_mfma_f32_16x16x32_bf16(a[m], b[n], acc[m][n], 0, 0, 0);
    __builtin_amdgcn_s_setprio(0);
    asm volatile("s_waitcnt lgkmcnt(0)" ::: "memory");
    __builtin_amdgcn_s_barrier();            // reads of buf kb done -> reusable
  }
#undef GSTAGE

  const int mat = blockIdx.y >> 3;   // 0=Q 1=K 2=V
  if (mat < 2) {
    unsigned short* dst = mat ? Kb : Qb;
    const float sc = mat ? 1.0f : 0.125f;
    const int h = ((colBase & 1023) + wc * 64) >> 6;
#pragma unroll
    for (int m = 0; m < 4; ++m) {
#pragma unroll
      for (int r = 0; r < 4; ++r) {
        int row = rowBase + wr * 64 + m * 16 + g * 4 + r;
        int bi = row >> 11, t = row & 2047;
        unsigned short* out = &dst[(size_t)((bi * NH + h) * SEQ + t) * DH];
#pragma unroll
        for (int n = 0; n < 2; ++n) {
          int j = n * 16 + lam;
          float c = cost[t * 32 + j], s = sint[t * 32 + j];
          float x0 = acc[m][n][r], x1 = acc[m][n + 2][r];
          out[j] = f2bf((x0 * c - x1 * s) * sc);
          out[j + 32] = f2bf((x1 * c + x0 * s) * sc);
        }
      }
    }
  } else {
    // V: transpose 128x128 via LDS (aliased over As), pad 44 to avoid conflicts
    unsigned short (*Vbuf)[44] = reinterpret_cast<unsigned short(*)[44]>(&As[0][0]);
    const int b = rowBase >> 11, t0 = rowBase & 2047;
#pragma unroll
    for (int cc = 0; cc < 4; ++cc) {
      __syncthreads();
      if (wc == (cc >> 1)) {
        const int n0 = (cc & 1) * 2;
#pragma unroll
        for (int m = 0; m < 4; ++m)
#pragma unroll
          for (int r = 0; r < 4; ++r)
#pragma unroll
            for (int n2 = 0; n2 < 2; ++n2)
              Vbuf[wr * 64 + m * 16 + g * 4 + r][n2 * 16 + lam] = f2bf(acc[m][n0 + n2][r]);
      }
      __syncthreads();
      const int colq0 = colBase - 2048 + cc * 32;
#pragma unroll
      for (int p2 = 0; p2 < 2; ++p2) {
        int ch = p2 * 256 + tid;
        int d = ch & 31, tq = (ch >> 5) * 8;
        unsigned short tmp[8];
#pragma unroll
        for (int i = 0; i < 8; ++i) tmp[i] = Vbuf[tq + i][d];
        int col = colq0 + d;
        int h = col >> 6, dd = col & 63;
        *reinterpret_cast<bf16x8*>(&Vtg[((size_t)(b * NH + h) * DH + dd) * SEQ + t0 + tq]) =
            *reinterpret_cast<bf16x8*>(tmp);
      }
    }
  }
}

// ---------------- causal flash attention: 128-kv tiles, swapped QK^T ----------------
// grid (32 bh, 16 pair). Pair (p, 31-p): nA+nB = 17 iterations, 33 subtile-works.
__global__ __launch_bounds__(256) void attn_kernel(
    const unsigned short* __restrict__ Qb, const unsigned short* __restrict__ Kb,
    const unsigned short* __restrict__ Vtg, unsigned short* __restrict__ Ob) {
  __shared__ unsigned short Ks[2][8192];   // [buf][128 kv][64 d], chunk ^ (row&7)
  __shared__ unsigned short Vs[2][8192];   // [buf][64 d][128 kv], chunk ^ (row&15)
  __shared__ unsigned short Ps[4][2048];   // per-wave [16 q][128 kv], chunk ^ (lam&15)

  const int tid = threadIdx.x;
  const int lane = tid & 63;
  const int w = tid >> 6;
  const int lam = lane & 15;
  const int g = lane >> 4;
  const int bh = blockIdx.x;
  const int p = blockIdx.y;
  const int qtA = p, qtB = 31 - p;
  const int nA = (p >> 1) + 1;
  const int nB = ((31 - p) >> 1) + 1;
  const int nT = nA + nB;                  // 17
  const int ql = w * 16 + lam;

  const unsigned short* kallbase = Kb + (size_t)bh * SEQ * DH;
  const unsigned short* vallbase = Vtg + (size_t)bh * DH * SEQ;

  bf16x8 qb0, qb1;
  f32x4 oacc[4], sa0[4], sa1[4];
  float mr, lr;

#define LOADQ(qt)                                                                     \
  {                                                                                   \
    const unsigned short* qrow = Qb + ((size_t)bh * SEQ + (qt) * 64 + w * 16 + lam) * DH; \
    qb0 = *reinterpret_cast<const bf16x8*>(&qrow[g * 8]);                             \
    qb1 = *reinterpret_cast<const bf16x8*>(&qrow[g * 8 + 32]);                        \
  }
#define RESET_STATE()                                                                 \
  {                                                                                   \
    _Pragma("unroll") for (int f = 0; f < 4; ++f) oacc[f] = (f32x4){0.f, 0.f, 0.f, 0.f}; \
    mr = -1e30f; lr = 0.f;                                                            \
  }
#define STAGE(buf, jt)                                                                \
  {                                                                                   \
    const unsigned short* kb2 = kallbase + (size_t)(jt) * 128 * DH;                   \
    const unsigned short* vb2 = vallbase + (size_t)(jt) * 128;                        \
    _Pragma("unroll") for (int c = 0; c < 4; ++c) {                                   \
      int id = c * 256 + w * 64 + lane;                                               \
      int kr = id >> 3, kq = id & 7;                                                  \
      GLOAD16(kb2 + kr * DH + ((kq ^ (kr & 7)) * 8), &Ks[buf][0] + id * 8);           \
      int vr = id >> 4, vq = id & 15;                                                 \
      GLOAD16(vb2 + (size_t)vr * SEQ + ((vq ^ (vr & 15)) * 8), &Vs[buf][0] + id * 8); \
    }                                                                                 \
  }
#define FLUSHO(qt)                                                                    \
  {                                                                                   \
    const int b = bh >> 4, h = bh & 15;                                               \
    float rinv = 1.0f / lr;                                                           \
    _Pragma("unroll") for (int r = 0; r < 4; ++r) {                                   \
      int n = (qt) * 64 + w * 16 + g * 4 + r;                                         \
      float inv = __shfl(rinv, g * 4 + r);                                            \
      unsigned short* orow = &Ob[(size_t)(b * SEQ + n) * DMODEL + h * DH];            \
      _Pragma("unroll") for (int f = 0; f < 4; ++f) orow[f * 16 + lam] = f2bf(oacc[f][r] * inv); \
    }                                                                                 \
  }

  RESET_STATE();
  LOADQ(qtA);
  STAGE(0, 0);
  asm volatile("s_waitcnt vmcnt(0)" ::: "memory");
  __syncthreads();

  int cur = 0;
  for (int i = 0; i < nT; ++i) {
    const int onA = (i < nA);
    const int qt = onA ? qtA : qtB;
    const int j = onA ? i : (i - nA);

    if (i + 1 < nT) {
      const int jn = (i + 1 < nA) ? (i + 1) : (i + 1 - nA);
      STAGE(cur ^ 1, jn);
    }

    const int t1 = 2 * j + 1;
    const bool diag0 = (2 * j == qt);
    const bool diag1 = (t1 == qt);
    const bool skip1 = (t1 > qt);

    // ---- S^T = K Q^T over 128 kv (two 64-subtiles) ----
#pragma unroll
    for (int f = 0; f < 4; ++f) {
      sa0[f] = (f32x4){0.f, 0.f, 0.f, 0.f};
      sa1[f] = (f32x4){0.f, 0.f, 0.f, 0.f};
    }
    __builtin_amdgcn_s_setprio(1);
#pragma unroll
    for (int f = 0; f < 4; ++f) {
      int kr = f * 16 + lam;
      bf16x8 k0 = *reinterpret_cast<bf16x8*>(&Ks[cur][kr * 64 + ((g ^ (kr & 7)) * 8)]);
      bf16x8 k1 = *reinterpret_cast<bf16x8*>(&Ks[cur][kr * 64 + (((g + 4) ^ (kr & 7)) * 8)]);
      sa0[f] = __builtin_amdgcn_mfma_f32_16x16x32_bf16(k0, qb0, sa0[f], 0, 0, 0);
      sa0[f] = __builtin_amdgcn_mfma_f32_16x16x32_bf16(k1, qb1, sa0[f], 0, 0, 0);
    }
    if (!skip1) {
#pragma unroll
      for (int f = 0; f < 4; ++f) {
        int kr = 64 + f * 16 + lam;
        bf16x8 k0 = *reinterpret_cast<bf16x8*>(&Ks[cur][kr * 64 + ((g ^ (kr & 7)) * 8)]);
        bf16x8 k1 = *reinterpret_cast<bf16x8*>(&Ks[cur][kr * 64 + (((g + 4) ^ (kr & 7)) * 8)]);
        sa1[f] = __builtin_amdgcn_mfma_f32_16x16x32_bf16(k0, qb0, sa1[f], 0, 0, 0);
        sa1[f] = __builtin_amdgcn_mfma_f32_16x16x32_bf16(k1, qb1, sa1[f], 0, 0, 0);
      }
    }
    __builtin_amdgcn_s_setprio(0);

    if (diag0) {
#pragma unroll
      for (int f = 0; f < 4; ++f)
#pragma unroll
        for (int r = 0; r < 4; ++r)
          if (f * 16 + g * 4 + r > ql) sa0[f][r] = -1e30f;
    }
    if (diag1) {
#pragma unroll
      for (int f = 0; f < 4; ++f)
#pragma unroll
        for (int r = 0; r < 4; ++r)
          if (f * 16 + g * 4 + r > ql) sa1[f][r] = -1e30f;
    }

    // ---- online softmax over up to 32 in-lane values + 2 shfl ----
    float mx = -1e30f;
#pragma unroll
    for (int f = 0; f < 4; ++f)
#pragma unroll
      for (int r = 0; r < 4; ++r) mx = fmaxf(mx, sa0[f][r]);
    if (!skip1) {
#pragma unroll
      for (int f = 0; f < 4; ++f)
#pragma unroll
        for (int r = 0; r < 4; ++r) mx = fmaxf(mx, sa1[f][r]);
    }
    mx = fmaxf(mx, __shfl_xor(mx, 16));
    mx = fmaxf(mx, __shfl_xor(mx, 32));
    float mn = fmaxf(mr, mx);
    float alpha = __expf(mr - mn);
    mr = mn;

    float sum = 0.f;
#pragma unroll
    for (int f = 0; f < 4; ++f)
#pragma unroll
      for (int r = 0; r < 4; ++r) {
        sa0[f][r] = __expf(sa0[f][r] - mn);
        sum += sa0[f][r];
      }
    if (!skip1) {
#pragma unroll
      for (int f = 0; f < 4; ++f)
#pragma unroll
        for (int r = 0; r < 4; ++r) {
          sa1[f][r] = __expf(sa1[f][r] - mn);
          sum += sa1[f][r];
        }
    }
    sum += __shfl_xor(sum, 16);
    sum += __shfl_xor(sum, 32);
    lr = lr * alpha + sum;

#pragma unroll
    for (int r = 0; r < 4; ++r) {
      float af = __shfl(alpha, g * 4 + r);
#pragma unroll
      for (int f = 0; f < 4; ++f) oacc[f][r] *= af;
    }

    // ---- pack P -> Ps (swizzled uint2 writes) ----
#pragma unroll
    for (int f = 0; f < 4; ++f) {
      uint2 u;
      u.x = pkbf(sa0[f][0], sa0[f][1]);
      u.y = pkbf(sa0[f][2], sa0[f][3]);
      int chunk = f * 2 + (g >> 1);
      *reinterpret_cast<uint2*>(
          &Ps[w][lam * 128 + ((chunk ^ (lam & 15)) * 8) + ((g & 1) * 4)]) = u;
    }
    if (!skip1) {
#pragma unroll
      for (int f = 0; f < 4; ++f) {
        uint2 u;
        u.x = pkbf(sa1[f][0], sa1[f][1]);
        u.y = pkbf(sa1[f][2], sa1[f][3]);
        int chunk = 8 + f * 2 + (g >> 1);
        *reinterpret_cast<uint2*>(
            &Ps[w][lam * 128 + ((chunk ^ (lam & 15)) * 8) + ((g & 1) * 4)]) = u;
      }
    }

    bf16x8 pa0 = *reinterpret_cast<bf16x8*>(&Ps[w][lam * 128 + ((g ^ (lam & 15)) * 8)]);
    bf16x8 pa1 = *reinterpret_cast<bf16x8*>(&Ps[w][lam * 128 + (((4 + g) ^ (lam & 15)) * 8)]);
    __builtin_amdgcn_s_setprio(1);
#pragma unroll
    for (int f = 0; f < 4; ++f) {
      int vr = f * 16 + lam;
      bf16x8 v0 = *reinterpret_cast<bf16x8*>(&Vs[cur][vr * 128 + ((g ^ (vr & 15)) * 8)]);
      bf16x8 v1 = *reinterpret_cast<bf16x8*>(&Vs[cur][vr * 128 + (((4 + g) ^ (vr & 15)) * 8)]);
      oacc[f] = __builtin_amdgcn_mfma_f32_16x16x32_bf16(pa0, v0, oacc[f], 0, 0, 0);
      oacc[f] = __builtin_amdgcn_mfma_f32_16x16x32_bf16(pa1, v1, oacc[f], 0, 0, 0);
    }
    __builtin_amdgcn_s_setprio(0);
    if (!skip1) {
      bf16x8 pa2 = *reinterpret_cast<bf16x8*>(&Ps[w][lam * 128 + (((8 + g) ^ (lam & 15)) * 8)]);
      bf16x8 pa3 = *reinterpret_cast<bf16x8*>(&Ps[w][lam * 128 + (((12 + g) ^ (lam & 15)) * 8)]);
      __builtin_amdgcn_s_setprio(1);
#pragma unroll
      for (int f = 0; f < 4; ++f) {
        int vr = f * 16 + lam;
        bf16x8 v2 = *reinterpret_cast<bf16x8*>(&Vs[cur][vr * 128 + (((8 + g) ^ (vr & 15)) * 8)]);
        bf16x8 v3 = *reinterpret_cast<bf16x8*>(&Vs[cur][vr * 128 + (((12 + g) ^ (vr & 15)) * 8)]);
        oacc[f] = __builtin_amdgcn_mfma_f32_16x16x32_bf16(pa2, v2, oacc[f], 0, 0, 0);
        oacc[f] = __builtin_amdgcn_mfma_f32_16x16x32_bf16(pa3, v3, oacc[f], 0, 0, 0);
      }
      __builtin_amdgcn_s_setprio(0);
    }

    if (i == nA - 1) {
      FLUSHO(qtA);
      RESET_STATE();
      LOADQ(qtB);
    }

    asm volatile("s_waitcnt vmcnt(0)" ::: "memory");
    __syncthreads();
    cur ^= 1;
  }
  FLUSHO(qtB);
#undef LOADQ
#undef RESET_STATE
#undef STAGE
#undef FLUSHO
}

// ------------- output GEMM: 3-deep counted-vmcnt pipeline -------------
__global__ __launch_bounds__(256) void gemm_out_kernel(
    const unsigned short* __restrict__ A, const unsigned short* __restrict__ BT,
    float* __restrict__ C) {
  __shared__ unsigned short As[3][4096];
  __shared__ unsigned short Bs[3][4096];

  const int tid = threadIdx.x;
  const int lane = tid & 63;
  const int w = tid >> 6;
  const int lam = lane & 15;
  const int g = lane >> 4;
  const int wr = w >> 1, wc = w & 1;
  const int rowBase = blockIdx.x * 128;
  const int colBase = blockIdx.y * 128;

  f32x4 acc[4][4];
#pragma unroll
  for (int m = 0; m < 4; ++m)
#pragma unroll
    for (int n = 0; n < 4; ++n) acc[m][n] = (f32x4){0.f, 0.f, 0.f, 0.f};

#define GSTAGE(buf, kk0)                                                               \
  {                                                                                    \
    _Pragma("unroll") for (int c = 0; c < 2; ++c) {                                    \
      int ch = c * 256 + w * 64 + lane;                                                \
      int row = ch >> 2, q = ch & 3;                                                   \
      GLOAD16(A + (size_t)(rowBase + row) * DMODEL + (kk0) + ((q ^ (row & 3)) * 8),    \
              &As[buf][0] + (c * 256 + w * 64) * 8);                                   \
      GLOAD16(BT + (size_t)(colBase + row) * DMODEL + (kk0) + ((q ^ (row & 3)) * 8),   \
              &Bs[buf][0] + (c * 256 + w * 64) * 8);                                   \
    }                                                                                  \
  }

  GSTAGE(0, 0);
  GSTAGE(1, 32);

  for (int kb = 0; kb < 32; ++kb) {
    if (kb + 2 < 32) {
      GSTAGE((kb + 2) % 3, (kb + 2) * 32);
      asm volatile("s_waitcnt vmcnt(8)" ::: "memory");
    } else if (kb + 1 < 32) {
      asm volatile("s_waitcnt vmcnt(4)" ::: "memory");
    } else {
      asm volatile("s_waitcnt vmcnt(0)" ::: "memory");
    }
    __builtin_amdgcn_s_barrier();
    const int cb = kb % 3;
    bf16x8 a[4], b[4];
    const int sw = (g ^ (lam & 3)) * 8;
#pragma unroll
    for (int m = 0; m < 4; ++m)
      a[m] = *reinterpret_cast<bf16x8*>(&As[cb][(wr * 64 + m * 16 + lam) * 32 + sw]);
#pragma unroll
    for (int n = 0; n < 4; ++n)
      b[n] = *reinterpret_cast<bf16x8*>(&Bs[cb][(wc * 64 + n * 16 + lam) * 32 + sw]);
    __builtin_amdgcn_s_setprio(1);
#pragma unroll
    for (int m = 0; m < 4; ++m)
#pragma unroll
      for (int n = 0; n < 4; ++n)
        acc[m][n] = __builtin_amdgcn_mfma_f32_16x16x32_bf16(a[m], b[n], acc[m][n], 0, 0, 0);
    __builtin_amdgcn_s_setprio(0);
    asm volatile("s_waitcnt lgkmcnt(0)" ::: "memory");
    __builtin_amdgcn_s_barrier();
  }
#undef GSTAGE

#pragma unroll
  for (int m = 0; m < 4; ++m)
#pragma unroll
    for (int r = 0; r < 4; ++r) {
      int row = rowBase + wr * 64 + m * 16 + g * 4 + r;
#pragma unroll
      for (int n = 0; n < 4; ++n)
        C[(size_t)row * DMODEL + colBase + wc * 64 + n * 16 + lam] = acc[m][n][r];
    }
}

extern "C" void kernel_launch(void* const* d_in, const int* in_sizes, int n_in,
                              void* d_out, int out_size, void* d_ws, size_t ws_size,
                              hipStream_t stream) {
  const float* x = (const float*)d_in[0];       // [2][2048][1024]
  const float* w_qkv = (const float*)d_in[1];   // [1024][3072]
  const float* w_out = (const float*)d_in[2];   // [1024][1024]
  float* out = (float*)d_out;

  char* ws = (char*)d_ws;
  const size_t MB = 1024 * 1024;
  unsigned short* WqkvT = (unsigned short*)(ws);             // 6MB  [phase1]
  float* cost = (float*)(ws + 6 * MB);
  float* sint = cost + SEQ * 32;
  unsigned short* Ob = (unsigned short*)(ws);                // 8MB  [after gemm_qkv]
  unsigned short* WoutT = (unsigned short*)(ws + 8 * MB);    // 2MB
  unsigned short* Qb = (unsigned short*)(ws + 10 * MB);      // 8MB
  unsigned short* Kb = (unsigned short*)(ws + 18 * MB);      // 8MB
  unsigned short* Vtg = (unsigned short*)(ws + 26 * MB);     // 8MB   [bh][d][t]
  unsigned short* Xb = (unsigned short*)d_out;               // scratch; overwritten by gemm_out

  prep_kernel<<<3328, 256, 0, stream>>>(x, w_qkv, w_out, Xb, WqkvT, WoutT, cost, sint);
  gemm_qkv_kernel<<<dim3(32, 24), 256, 0, stream>>>(Xb, WqkvT, Qb, Kb, Vtg, cost, sint);
  attn_kernel<<<dim3(32, 16), 256, 0, stream>>>(Qb, Kb, Vtg, Ob);
  gemm_out_kernel<<<dim3(32, 8), 256, 0, stream>>>(Ob, WoutT, out);
}